// Round 1
// baseline (922.397 us; speedup 1.0000x reference)
//
#include <hip/hip_runtime.h>
#include <hip/hip_bf16.h>
#include <math.h>

typedef float f32x4 __attribute__((ext_vector_type(4)));
typedef _Float16 f16x8 __attribute__((ext_vector_type(8)));

#define TT 1024
#define DD 1024

// ---------------- generic f16-MFMA GEMM: C = A(MxK) @ B(KxN) + bias [+res] [+gelu] ----------------
// LDS tiles stored as 128 rows x 32 k (f16), XOR-swizzled:
//   byte = row*64 + 16*((k>>3) ^ ((row>>1)&3)) + 2*(k&7)
static __device__ __forceinline__ int swz(int row, int k) {
  return row * 32 + (((k >> 3) ^ ((row >> 1) & 3)) << 3) + (k & 7);
}

__global__ __launch_bounds__(256) void gemm_f16(
    const float* __restrict__ A, const float* __restrict__ B,
    const float* __restrict__ bias, const float* __restrict__ residual,
    float* __restrict__ C, int M, int N, int K, int act) {
  __shared__ __align__(16) _Float16 As[128 * 32];
  __shared__ __align__(16) _Float16 Bs[128 * 32];
  const int tid = threadIdx.x;
  const int lane = tid & 63;
  const int wid = tid >> 6;
  const int wr = wid >> 1, wc = wid & 1;           // 2x2 waves over 128x128
  const int g = lane >> 4, l16 = lane & 15;
  const int row0 = blockIdx.y * 128, col0 = blockIdx.x * 128;

  f32x4 acc[4][4];
#pragma unroll
  for (int m = 0; m < 4; ++m)
#pragma unroll
    for (int n = 0; n < 4; ++n) acc[m][n] = (f32x4){0.f, 0.f, 0.f, 0.f};

  const int ar = tid >> 1, ah = tid & 1;           // A stage: row, k-half
  const int bn = tid & 127, bg = (tid >> 7) * 2;   // B stage: col, k-octet base

  for (int k0 = 0; k0 < K; k0 += 32) {
    // stage A (coalesced float4 row reads -> swizzled b128 LDS writes)
#pragma unroll
    for (int t2 = 0; t2 < 2; ++t2) {
      const int gk = ah * 2 + t2;
      const float* ap = A + (size_t)(row0 + ar) * K + k0 + gk * 8;
      const float4 a0 = *(const float4*)ap;
      const float4 a1 = *(const float4*)(ap + 4);
      f16x8 pk;
      pk[0] = (_Float16)a0.x; pk[1] = (_Float16)a0.y; pk[2] = (_Float16)a0.z; pk[3] = (_Float16)a0.w;
      pk[4] = (_Float16)a1.x; pk[5] = (_Float16)a1.y; pk[6] = (_Float16)a1.z; pk[7] = (_Float16)a1.w;
      *(f16x8*)(As + swz(ar, gk * 8)) = pk;
    }
    // stage B transposed (coalesced scalar col reads -> swizzled b128 LDS writes)
#pragma unroll
    for (int t2 = 0; t2 < 2; ++t2) {
      const int gk = bg + t2;
      const float* bp = B + (size_t)(k0 + gk * 8) * N + col0 + bn;
      f16x8 pk;
#pragma unroll
      for (int m2 = 0; m2 < 8; ++m2) pk[m2] = (_Float16)bp[(size_t)m2 * N];
      *(f16x8*)(Bs + swz(bn, gk * 8)) = pk;
    }
    __syncthreads();
    f16x8 af[4], bfv[4];
#pragma unroll
    for (int m = 0; m < 4; ++m) af[m] = *(const f16x8*)(As + swz(wr * 64 + m * 16 + l16, g * 8));
#pragma unroll
    for (int n = 0; n < 4; ++n) bfv[n] = *(const f16x8*)(Bs + swz(wc * 64 + n * 16 + l16, g * 8));
#pragma unroll
    for (int m = 0; m < 4; ++m)
#pragma unroll
      for (int n = 0; n < 4; ++n)
        acc[m][n] = __builtin_amdgcn_mfma_f32_16x16x32_f16(af[m], bfv[n], acc[m][n], 0, 0, 0);
    __syncthreads();
  }
  // epilogue: C/D frag layout col=lane&15, row=4*(lane>>4)+reg
#pragma unroll
  for (int m = 0; m < 4; ++m) {
#pragma unroll
    for (int n = 0; n < 4; ++n) {
      const int col = col0 + wc * 64 + n * 16 + l16;
      const float bv = bias ? bias[col] : 0.f;
#pragma unroll
      for (int rg = 0; rg < 4; ++rg) {
        const int row = row0 + wr * 64 + m * 16 + g * 4 + rg;
        const size_t off = (size_t)row * N + col;
        float v = acc[m][n][rg] + bv;
        if (residual) v += residual[off];
        if (act == 1) v = 0.5f * v * (1.f + erff(v * 0.70710678118654752f));
        C[off] = v;
      }
    }
  }
}

// ---------------- LayerNorm over D=1024, one row per 256-thread block ----------------
__global__ __launch_bounds__(256) void ln_kernel(const float* __restrict__ in,
    const float* __restrict__ gw, const float* __restrict__ bw, float* __restrict__ out) {
  const int row = blockIdx.x, tid = threadIdx.x;
  const float* x = in + (size_t)row * DD;
  const float4 v = *(const float4*)(x + tid * 4);
  float s = v.x + v.y + v.z + v.w;
  float sq = v.x * v.x + v.y * v.y + v.z * v.z + v.w * v.w;
#pragma unroll
  for (int off = 32; off >= 1; off >>= 1) { s += __shfl_xor(s, off); sq += __shfl_xor(sq, off); }
  __shared__ float red[8];
  const int lane = tid & 63, wv = tid >> 6;
  if (lane == 0) { red[wv] = s; red[4 + wv] = sq; }
  __syncthreads();
  s = red[0] + red[1] + red[2] + red[3];
  sq = red[4] + red[5] + red[6] + red[7];
  const float mean = s * (1.f / 1024.f);
  const float var = sq * (1.f / 1024.f) - mean * mean;
  const float rstd = rsqrtf(var + 1e-5f);
  const float4 g4 = *(const float4*)(gw + tid * 4);
  const float4 b4 = *(const float4*)(bw + tid * 4);
  float4 o;
  o.x = (v.x - mean) * rstd * g4.x + b4.x;
  o.y = (v.y - mean) * rstd * g4.y + b4.y;
  o.z = (v.z - mean) * rstd * g4.z + b4.z;
  o.w = (v.w - mean) * rstd * g4.w + b4.w;
  *(float4*)(out + (size_t)row * DD + tid * 4) = o;
}

// ---------------- causal flash attention (fp32 VALU), 4 q-rows per block ----------------
// qkv: (B,T,3,H,64) fp32. seq_out: (B,T,D).
__global__ __launch_bounds__(256) void attn_kernel(const float* __restrict__ qkv,
                                                   float* __restrict__ seq_out) {
  __shared__ __align__(16) float Kl[64 * 64];   // [s][d] swizzled
  __shared__ __align__(16) float Vt[64 * 64];   // [d][s] swizzled
  __shared__ __align__(16) float ql[4][64];
  __shared__ __align__(16) float pl[4][1024];
  const int tid = threadIdx.x;
  const int lane = tid & 63, w = tid >> 6;
  const int rt = blockIdx.x, hh = blockIdx.y, bb = blockIdx.z;
  const int r = rt * 4 + w;                    // this wave's query row
  const int nt = (rt >> 4) + 1;                // K tiles needed (uniform in block)

  ql[w][lane] = qkv[((size_t)(bb * TT + r) * 3 + 0) * DD + hh * 64 + lane] * 0.125f;

  float mx = -INFINITY;
  for (int tt = 0; tt < nt; ++tt) {
    __syncthreads();
    {
      const int si = tid >> 2, dqb = tid & 3;
#pragma unroll
      for (int q4 = 0; q4 < 4; ++q4) {
        const int dq = dqb + q4 * 4;
        const float4 kv = *(const float4*)(qkv + ((size_t)(bb * TT + tt * 64 + si) * 3 + 1) * DD + hh * 64 + dq * 4);
        *(float4*)(Kl + si * 64 + ((dq ^ (si & 15)) << 2)) = kv;
      }
    }
    __syncthreads();
    float acc = 0.f;
#pragma unroll
    for (int d4 = 0; d4 < 16; ++d4) {
      const float4 q4 = *(const float4*)(&ql[w][d4 * 4]);
      const float4 k4 = *(const float4*)(Kl + lane * 64 + ((d4 ^ (lane & 15)) << 2));
      acc += q4.x * k4.x + q4.y * k4.y + q4.z * k4.z + q4.w * k4.w;
    }
    const int s = tt * 64 + lane;
    const float val = (s <= r) ? acc : -INFINITY;
    pl[w][tt * 64 + lane] = val;
    mx = fmaxf(mx, val);
  }
#pragma unroll
  for (int off = 32; off >= 1; off >>= 1) mx = fmaxf(mx, __shfl_xor(mx, off));
  float sum = 0.f;
  for (int tt = 0; tt < nt; ++tt) {
    const float e = __expf(pl[w][tt * 64 + lane] - mx);
    pl[w][tt * 64 + lane] = e;
    sum += e;
  }
#pragma unroll
  for (int off = 32; off >= 1; off >>= 1) sum += __shfl_xor(sum, off);
  const float inv = 1.f / sum;

  float o = 0.f;
  for (int tt = 0; tt < nt; ++tt) {
    __syncthreads();
    {
      const int d = tid & 63, sqb = tid >> 6;
#pragma unroll
      for (int q4 = 0; q4 < 4; ++q4) {
        const int sq = sqb + q4 * 4;
        float4 vv;
        vv.x = qkv[((size_t)(bb * TT + tt * 64 + sq * 4 + 0) * 3 + 2) * DD + hh * 64 + d];
        vv.y = qkv[((size_t)(bb * TT + tt * 64 + sq * 4 + 1) * 3 + 2) * DD + hh * 64 + d];
        vv.z = qkv[((size_t)(bb * TT + tt * 64 + sq * 4 + 2) * 3 + 2) * DD + hh * 64 + d];
        vv.w = qkv[((size_t)(bb * TT + tt * 64 + sq * 4 + 3) * 3 + 2) * DD + hh * 64 + d];
        *(float4*)(Vt + d * 64 + ((sq ^ (d & 15)) << 2)) = vv;
      }
    }
    __syncthreads();
#pragma unroll
    for (int j4 = 0; j4 < 16; ++j4) {
      const float4 p4 = *(const float4*)(&pl[w][tt * 64 + j4 * 4]);
      const float4 v4 = *(const float4*)(Vt + lane * 64 + ((j4 ^ (lane & 15)) << 2));
      o += p4.x * v4.x + p4.y * v4.y + p4.z * v4.z + p4.w * v4.w;
    }
  }
  seq_out[(size_t)(bb * TT + r) * DD + hh * 64 + lane] = o * inv;
}

// ---------------- pack [W1w|W2w|W1r|W2r|Wmg|0...] into 1024x512 + bias 512 ----------------
__global__ void prep_small(const float* __restrict__ W1w, const float* __restrict__ W2w,
                           const float* __restrict__ W1r, const float* __restrict__ W2r,
                           const float* __restrict__ Wmg, const float* __restrict__ bmg,
                           float* __restrict__ Wsm, float* __restrict__ bsm) {
  const int i = blockIdx.x * 256 + threadIdx.x;
  if (i < 1024 * 512) {
    const int row = i >> 9, col = i & 511;
    float v = 0.f;
    if (col < 64) v = W1w[row * 64 + col];
    else if (col < 128) v = W2w[row * 64 + col - 64];
    else if (col < 192) v = W1r[row * 64 + col - 128];
    else if (col < 256) v = W2r[row * 64 + col - 192];
    else if (col < 272) v = Wmg[row * 16 + col - 256];
    Wsm[i] = v;
  } else if (i < 1024 * 512 + 512) {
    const int col = i - 1024 * 512;
    bsm[col] = (col >= 256 && col < 272) ? bmg[col - 256] : 0.f;
  }
}

// ---------------- exterior products -> Jw, rd, gate ----------------
static __device__ __forceinline__ void ext6(const float* a, const float* b, float* L) {
  L[0] = a[0] * b[1] - a[1] * b[0];
  L[1] = a[0] * b[2] - a[2] * b[0];
  L[2] = a[0] * b[3] - a[3] * b[0];
  L[3] = a[1] * b[2] - a[2] * b[1];
  L[4] = a[1] * b[3] - a[3] * b[1];
  L[5] = a[2] * b[3] - a[3] * b[2];
  const float n = sqrtf(L[0]*L[0] + L[1]*L[1] + L[2]*L[2] + L[3]*L[3] + L[4]*L[4] + L[5]*L[5]);
  const float s = 1.f / fmaxf(n, 1e-12f);
#pragma unroll
  for (int i = 0; i < 6; ++i) L[i] *= s;
}

__global__ void lines_post(const float* __restrict__ lo, float* __restrict__ jw,
                           float* __restrict__ rdv, float* __restrict__ gate) {
  const int idx = blockIdx.x * 256 + threadIdx.x;  // (b*T+t)*16 + h
  const int h = idx & 15;
  const int bt = idx >> 4;
  const int t = bt & 1023;
  const int b = bt >> 10;
  const float* row = lo + (size_t)bt * 512;
  float w1[4] = {0.f, 0.f, 0.f, 0.f}, w2[4], r1[4], r2[4];
  if (t > 0) {
#pragma unroll
    for (int i = 0; i < 4; ++i) w1[i] = row[-512 + h * 4 + i];  // shifted: u1[t-1]
  }
#pragma unroll
  for (int i = 0; i < 4; ++i) {
    w2[i] = row[64 + h * 4 + i];
    r1[i] = row[128 + h * 4 + i];
    r2[i] = row[192 + h * 4 + i];
  }
  const float gp = row[256 + h];
  float wl[6], rl[6];
  ext6(w1, w2, wl);
  ext6(r1, r2, rl);
  const size_t o = ((size_t)(b * 16 + h) * 1024 + t) * 6;
  jw[o + 0] =  wl[5]; jw[o + 1] = -wl[4]; jw[o + 2] =  wl[3];
  jw[o + 3] =  wl[2]; jw[o + 4] = -wl[1]; jw[o + 5] =  wl[0];
#pragma unroll
  for (int i = 0; i < 6; ++i) rdv[o + i] = rl[i];
  gate[idx] = 1.f / (1.f + __expf(-gp));
}

// ---------------- Gram memory scan: one wave per (b,h); lanes 0..5 own M columns ----------------
__global__ __launch_bounds__(64) void gram_scan(const float* __restrict__ jwv,
    const float* __restrict__ rdv, const float* __restrict__ decay_logits,
    const float* __restrict__ iter_mix, float* __restrict__ mem_score) {
  const int h = blockIdx.x & 15, b = blockIdx.x >> 4;
  const int lane = threadIdx.x;
  const float decay = 1.f / (1.f + __expf(-decay_logits[h]));
  const float alpha = 1.f / (1.f + __expf(-iter_mix[0]));
  __shared__ float jws[64][8], rds[64][8];
  const size_t base = (size_t)(b * 16 + h) * 1024 * 6;
  const int j = lane & 7;
  float Mc[6] = {0.f, 0.f, 0.f, 0.f, 0.f, 0.f};
  for (int ttile = 0; ttile < 16; ++ttile) {
    __syncthreads();
    {
      const size_t t6 = base + (size_t)(ttile * 64 + lane) * 6;
#pragma unroll
      for (int i = 0; i < 6; ++i) { jws[lane][i] = jwv[t6 + i]; rds[lane][i] = rdv[t6 + i]; }
      jws[lane][6] = 0.f; jws[lane][7] = 0.f; rds[lane][6] = 0.f; rds[lane][7] = 0.f;
    }
    __syncthreads();
    for (int tl = 0; tl < 64; ++tl) {
      float jv[6], rv[6];
#pragma unroll
      for (int i = 0; i < 6; ++i) { jv[i] = jws[tl][i]; rv[i] = rds[tl][i]; }
      const float jj = jws[tl][j];
      const float rj = rds[tl][j];
      // score with state BEFORE updating (strictly-past M)
      float rdM = 0.f;
#pragma unroll
      for (int i = 0; i < 6; ++i) rdM += rv[i] * Mc[i];
      float s1 = rdM * rj, s2 = rdM * rdM;
      s1 += __shfl_xor(s1, 1, 8); s1 += __shfl_xor(s1, 2, 8); s1 += __shfl_xor(s1, 4, 8);
      s2 += __shfl_xor(s2, 1, 8); s2 += __shfl_xor(s2, 2, 8); s2 += __shfl_xor(s2, 4, 8);
      if (lane == 0)
        mem_score[(size_t)(b * 16 + h) * 1024 + ttile * 64 + tl] = (1.f - alpha) * s1 + alpha * s2;
      // M = decay * (M + Jw[t] Jw[t]^T)
#pragma unroll
      for (int i = 0; i < 6; ++i) Mc[i] = decay * (Mc[i] + jv[i] * jj);
    }
  }
}

// ---------------- gated mean over heads ----------------
__global__ void gmean_kernel(const float* __restrict__ ms, const float* __restrict__ gate,
    const float* __restrict__ mem_scale, float* __restrict__ gm) {
  const int bt = blockIdx.x * 256 + threadIdx.x;  // 0..2047
  const int b = bt >> 10, t = bt & 1023;
  float acc = 0.f;
#pragma unroll
  for (int h = 0; h < 16; ++h) {
    const float sc = ms[(size_t)(b * 16 + h) * 1024 + t];
    const float gt = gate[(size_t)bt * 16 + h];
    acc += (1.f / (1.f + __expf(-sc * mem_scale[h]))) * gt;
  }
  gm[bt] = acc * (1.f / 16.f);
}

// ---------------- attnin = seq_out + gmean * mem_val ----------------
__global__ void combine_kernel(const float* __restrict__ seq, const float* __restrict__ mv,
    const float* __restrict__ gm, float* __restrict__ outp) {
  const int i = blockIdx.x * 256 + threadIdx.x;  // float4 index, 524288 total
  const float g = gm[i >> 8];
  const float4 s4 = *(const float4*)(seq + (size_t)i * 4);
  const float4 m4 = *(const float4*)(mv + (size_t)i * 4);
  float4 o;
  o.x = s4.x + g * m4.x;
  o.y = s4.y + g * m4.y;
  o.z = s4.z + g * m4.z;
  o.w = s4.w + g * m4.w;
  *(float4*)(outp + (size_t)i * 4) = o;
}

extern "C" void kernel_launch(void* const* d_in, const int* in_sizes, int n_in,
                              void* d_out, int out_size, void* d_ws, size_t ws_size,
                              hipStream_t stream) {
  (void)in_sizes; (void)n_in; (void)out_size; (void)ws_size;
  const float* x       = (const float*)d_in[0];
  const float* ln1_g   = (const float*)d_in[1];
  const float* ln1_b   = (const float*)d_in[2];
  const float* Wqkv    = (const float*)d_in[3];
  const float* bqkv    = (const float*)d_in[4];
  const float* W1w     = (const float*)d_in[5];
  const float* W2w     = (const float*)d_in[6];
  const float* W1r     = (const float*)d_in[7];
  const float* W2r     = (const float*)d_in[8];
  const float* Wmv     = (const float*)d_in[9];
  const float* bmv     = (const float*)d_in[10];
  const float* Wmg     = (const float*)d_in[11];
  const float* bmg     = (const float*)d_in[12];
  const float* mscale  = (const float*)d_in[13];
  const float* itermix = (const float*)d_in[14];
  const float* dlogits = (const float*)d_in[15];
  const float* Wout    = (const float*)d_in[16];
  const float* bout    = (const float*)d_in[17];
  const float* ln2_g   = (const float*)d_in[18];
  const float* ln2_b   = (const float*)d_in[19];
  const float* Wfc     = (const float*)d_in[20];
  const float* bfc     = (const float*)d_in[21];
  const float* Wproj   = (const float*)d_in[22];
  const float* bproj   = (const float*)d_in[23];
  float* out = (float*)d_out;
  float* ws = (float*)d_ws;

  const size_t M1 = 1u << 20;
  float* h     = ws;                       // 2M floats (h -> attnin -> h2)
  float* qkv   = ws + 2 * M1;              // 6M
  float* fc    = ws + 2 * M1;              // 8M (reuses qkv+seq after they die)
  float* seq   = ws + 8 * M1;              // 2M
  float* lines = ws + 10 * M1;             // 1M
  float* mv    = ws + 11 * M1;             // 2M
  float* jw    = ws + 13 * M1;             // 196608
  float* rd    = ws + 13 * M1 + 262144;    // 196608
  float* gate  = ws + 13 * M1 + 524288;    // 32768
  float* ms    = ws + 13 * M1 + 557056;    // 32768
  float* gm    = ws + 13 * M1 + 589824;    // 2048
  float* Wsm   = ws + 13 * M1 + 655360;    // 524288
  float* bsm   = ws + 13 * M1 + 1179648;   // 512
  float* y     = ws + 14 * M1 + 262144;    // 2M

  prep_small<<<2051, 256, 0, stream>>>(W1w, W2w, W1r, W2r, Wmg, bmg, Wsm, bsm);
  ln_kernel<<<2048, 256, 0, stream>>>(x, ln1_g, ln1_b, h);
  gemm_f16<<<dim3(24, 16), 256, 0, stream>>>(h, Wqkv, bqkv, nullptr, qkv, 2048, 3072, 1024, 0);
  gemm_f16<<<dim3(4, 16), 256, 0, stream>>>(h, Wsm, bsm, nullptr, lines, 2048, 512, 1024, 0);
  gemm_f16<<<dim3(8, 16), 256, 0, stream>>>(h, Wmv, bmv, nullptr, mv, 2048, 1024, 1024, 0);
  attn_kernel<<<dim3(256, 16, 2), 256, 0, stream>>>(qkv, seq);
  lines_post<<<128, 256, 0, stream>>>(lines, jw, rd, gate);
  gram_scan<<<32, 64, 0, stream>>>(jw, rd, dlogits, itermix, ms);
  gmean_kernel<<<8, 256, 0, stream>>>(ms, gate, mscale, gm);
  combine_kernel<<<2048, 256, 0, stream>>>(seq, mv, gm, h);
  gemm_f16<<<dim3(8, 16), 256, 0, stream>>>(h, Wout, bout, x, y, 2048, 1024, 1024, 0);
  ln_kernel<<<2048, 256, 0, stream>>>(y, ln2_g, ln2_b, h);
  gemm_f16<<<dim3(32, 16), 256, 0, stream>>>(h, Wfc, bfc, nullptr, fc, 2048, 4096, 1024, 1);
  gemm_f16<<<dim3(8, 16), 256, 0, stream>>>(fc, Wproj, bproj, y, out, 2048, 1024, 4096, 0);
}

// Round 2
// 579.981 us; speedup vs baseline: 1.5904x; 1.5904x over previous
//
#include <hip/hip_runtime.h>
#include <hip/hip_bf16.h>
#include <math.h>

typedef float f32x4 __attribute__((ext_vector_type(4)));
typedef _Float16 f16x8 __attribute__((ext_vector_type(8)));
typedef _Float16 f16x4 __attribute__((ext_vector_type(4)));

#define TT 1024
#define DD 1024
#define QS 4608   // mega GEMM output row stride: [qkv 3072 | lines 512 | mv 1024]

// ---------------- generic f16-MFMA GEMM: C = A(MxK) @ B(KxN) + bias [+res] [+gelu] ----------------
static __device__ __forceinline__ int swz(int row, int k) {
  return row * 32 + (((k >> 3) ^ ((row >> 1) & 3)) << 3) + (k & 7);
}

__global__ __launch_bounds__(256) void gemm_f16(
    const float* __restrict__ A, const float* __restrict__ B,
    const float* __restrict__ bias, const float* __restrict__ residual,
    float* __restrict__ C, int M, int N, int K, int act) {
  __shared__ __align__(16) _Float16 As[128 * 32];
  __shared__ __align__(16) _Float16 Bs[128 * 32];
  const int tid = threadIdx.x;
  const int lane = tid & 63;
  const int wid = tid >> 6;
  const int wr = wid >> 1, wc = wid & 1;           // 2x2 waves over 128x128
  const int g = lane >> 4, l16 = lane & 15;
  const int row0 = blockIdx.y * 128, col0 = blockIdx.x * 128;

  f32x4 acc[4][4];
#pragma unroll
  for (int m = 0; m < 4; ++m)
#pragma unroll
    for (int n = 0; n < 4; ++n) acc[m][n] = (f32x4){0.f, 0.f, 0.f, 0.f};

  const int ar = tid >> 1, ah = tid & 1;           // A stage: row, k-half
  const int bn = tid & 127, bg = (tid >> 7) * 2;   // B stage: col, k-octet base

  for (int k0 = 0; k0 < K; k0 += 32) {
#pragma unroll
    for (int t2 = 0; t2 < 2; ++t2) {
      const int gk = ah * 2 + t2;
      const float* ap = A + (size_t)(row0 + ar) * K + k0 + gk * 8;
      const float4 a0 = *(const float4*)ap;
      const float4 a1 = *(const float4*)(ap + 4);
      f16x8 pk;
      pk[0] = (_Float16)a0.x; pk[1] = (_Float16)a0.y; pk[2] = (_Float16)a0.z; pk[3] = (_Float16)a0.w;
      pk[4] = (_Float16)a1.x; pk[5] = (_Float16)a1.y; pk[6] = (_Float16)a1.z; pk[7] = (_Float16)a1.w;
      *(f16x8*)(As + swz(ar, gk * 8)) = pk;
    }
#pragma unroll
    for (int t2 = 0; t2 < 2; ++t2) {
      const int gk = bg + t2;
      const float* bp = B + (size_t)(k0 + gk * 8) * N + col0 + bn;
      f16x8 pk;
#pragma unroll
      for (int m2 = 0; m2 < 8; ++m2) pk[m2] = (_Float16)bp[(size_t)m2 * N];
      *(f16x8*)(Bs + swz(bn, gk * 8)) = pk;
    }
    __syncthreads();
    f16x8 af[4], bfv[4];
#pragma unroll
    for (int m = 0; m < 4; ++m) af[m] = *(const f16x8*)(As + swz(wr * 64 + m * 16 + l16, g * 8));
#pragma unroll
    for (int n = 0; n < 4; ++n) bfv[n] = *(const f16x8*)(Bs + swz(wc * 64 + n * 16 + l16, g * 8));
#pragma unroll
    for (int m = 0; m < 4; ++m)
#pragma unroll
      for (int n = 0; n < 4; ++n)
        acc[m][n] = __builtin_amdgcn_mfma_f32_16x16x32_f16(af[m], bfv[n], acc[m][n], 0, 0, 0);
    __syncthreads();
  }
#pragma unroll
  for (int m = 0; m < 4; ++m) {
#pragma unroll
    for (int n = 0; n < 4; ++n) {
      const int col = col0 + wc * 64 + n * 16 + l16;
      const float bv = bias ? bias[col] : 0.f;
#pragma unroll
      for (int rg = 0; rg < 4; ++rg) {
        const int row = row0 + wr * 64 + m * 16 + g * 4 + rg;
        const size_t off = (size_t)row * N + col;
        float v = acc[m][n][rg] + bv;
        if (residual) v += residual[off];
        if (act == 1) v = 0.5f * v * (1.f + erff(v * 0.70710678118654752f));
        C[off] = v;
      }
    }
  }
}

// ---------------- LayerNorm over D=1024, one row per 256-thread block ----------------
__global__ __launch_bounds__(256) void ln_kernel(const float* __restrict__ in,
    const float* __restrict__ gw, const float* __restrict__ bw, float* __restrict__ out) {
  const int row = blockIdx.x, tid = threadIdx.x;
  const float* x = in + (size_t)row * DD;
  const float4 v = *(const float4*)(x + tid * 4);
  float s = v.x + v.y + v.z + v.w;
  float sq = v.x * v.x + v.y * v.y + v.z * v.z + v.w * v.w;
#pragma unroll
  for (int off = 32; off >= 1; off >>= 1) { s += __shfl_xor(s, off); sq += __shfl_xor(sq, off); }
  __shared__ float red[8];
  const int lane = tid & 63, wv = tid >> 6;
  if (lane == 0) { red[wv] = s; red[4 + wv] = sq; }
  __syncthreads();
  s = red[0] + red[1] + red[2] + red[3];
  sq = red[4] + red[5] + red[6] + red[7];
  const float mean = s * (1.f / 1024.f);
  const float var = sq * (1.f / 1024.f) - mean * mean;
  const float rstd = rsqrtf(var + 1e-5f);
  const float4 g4 = *(const float4*)(gw + tid * 4);
  const float4 b4 = *(const float4*)(bw + tid * 4);
  float4 o;
  o.x = (v.x - mean) * rstd * g4.x + b4.x;
  o.y = (v.y - mean) * rstd * g4.y + b4.y;
  o.z = (v.z - mean) * rstd * g4.z + b4.z;
  o.w = (v.w - mean) * rstd * g4.w + b4.w;
  *(float4*)(out + (size_t)row * DD + tid * 4) = o;
}

// ---------------- MFMA f16 causal flash attention ----------------
// block = (qt, h, b): 64 q-rows, 4 waves x 16 rows. K-tiles of 64 keys.
// Kl[key][dh], Vt[dh][key], Pl[wave][qrow][key] -- all XOR-swizzled f16.
static __device__ __forceinline__ int swzA(int row, int k) {
  return row * 64 + ((((k >> 3) ^ row) & 7) << 3) + (k & 7);
}
static __device__ __forceinline__ int swzV(int row, int k) {
  return row * 64 + ((((k >> 3) ^ row ^ (row >> 3)) & 7) << 3) + (k & 7);
}

__global__ __launch_bounds__(256) void attn_mfma(const float* __restrict__ qkv,
                                                 float* __restrict__ seq_out) {
  __shared__ __align__(16) _Float16 Kl[64 * 64];
  __shared__ __align__(16) _Float16 Vt[64 * 64];
  __shared__ __align__(16) _Float16 Pl[4][16 * 64];
  const int tid = threadIdx.x, lane = tid & 63, wq = tid >> 6;
  const int g = lane >> 4, l16 = lane & 15;
  const int qt = blockIdx.x, hh = blockIdx.y, bb = blockIdx.z;
  const int nt = qt + 1;

  // Q fragments (A layout: row=l16, k=ks*32+g*8+j), pre-scaled by dh^-0.5
  f16x8 qf[2];
  {
    const float* qp = qkv + (size_t)(bb * TT + qt * 64 + wq * 16 + l16) * QS + hh * 64;
#pragma unroll
    for (int ks = 0; ks < 2; ++ks) {
      const float4 a0 = *(const float4*)(qp + ks * 32 + g * 8);
      const float4 a1 = *(const float4*)(qp + ks * 32 + g * 8 + 4);
      qf[ks][0] = (_Float16)(a0.x * 0.125f); qf[ks][1] = (_Float16)(a0.y * 0.125f);
      qf[ks][2] = (_Float16)(a0.z * 0.125f); qf[ks][3] = (_Float16)(a0.w * 0.125f);
      qf[ks][4] = (_Float16)(a1.x * 0.125f); qf[ks][5] = (_Float16)(a1.y * 0.125f);
      qf[ks][6] = (_Float16)(a1.z * 0.125f); qf[ks][7] = (_Float16)(a1.w * 0.125f);
    }
  }

  f32x4 oacc[4];
#pragma unroll
  for (int n = 0; n < 4; ++n) oacc[n] = (f32x4){0.f, 0.f, 0.f, 0.f};
  float m[4] = {-INFINITY, -INFINITY, -INFINITY, -INFINITY};
  float l[4] = {0.f, 0.f, 0.f, 0.f};

  const int skey = tid >> 2, sc4 = tid & 3;

  for (int tt = 0; tt < nt; ++tt) {
    if (tt) __syncthreads();
    {  // stage K [key][dh] and V^T [dh][key]
      const float* kp = qkv + (size_t)(bb * TT + tt * 64 + skey) * QS + hh * 64 + 1024;
      const float* vp = kp + 1024;
#pragma unroll
      for (int ii = 0; ii < 4; ++ii) {
        const int d0 = sc4 * 4 + ii * 16;
        const float4 kv = *(const float4*)(kp + d0);
        f16x4 k4;
        k4[0] = (_Float16)kv.x; k4[1] = (_Float16)kv.y; k4[2] = (_Float16)kv.z; k4[3] = (_Float16)kv.w;
        *(f16x4*)(Kl + swzA(skey, d0)) = k4;
        const float4 vv = *(const float4*)(vp + d0);
        Vt[swzV(d0 + 0, skey)] = (_Float16)vv.x;
        Vt[swzV(d0 + 1, skey)] = (_Float16)vv.y;
        Vt[swzV(d0 + 2, skey)] = (_Float16)vv.z;
        Vt[swzV(d0 + 3, skey)] = (_Float16)vv.w;
      }
    }
    __syncthreads();
    // S = Q K^T  (C layout: row = g*4+reg, col = n*16+l16)
    f32x4 s[4];
#pragma unroll
    for (int n = 0; n < 4; ++n) s[n] = (f32x4){0.f, 0.f, 0.f, 0.f};
#pragma unroll
    for (int ks = 0; ks < 2; ++ks) {
      f16x8 kf[4];
#pragma unroll
      for (int n = 0; n < 4; ++n) kf[n] = *(const f16x8*)(Kl + swzA(n * 16 + l16, ks * 32 + g * 8));
#pragma unroll
      for (int n = 0; n < 4; ++n)
        s[n] = __builtin_amdgcn_mfma_f32_16x16x32_f16(qf[ks], kf[n], s[n], 0, 0, 0);
    }
    if (tt == qt) {  // causal mask on diagonal tile
      const int rloc = wq * 16 + g * 4;
#pragma unroll
      for (int n = 0; n < 4; ++n) {
        const int cloc = n * 16 + l16;
#pragma unroll
        for (int reg = 0; reg < 4; ++reg)
          if (cloc > rloc + reg) s[n][reg] = -INFINITY;
      }
    }
    // online softmax (row reductions across the 16 lanes sharing g)
    float f[4];
#pragma unroll
    for (int reg = 0; reg < 4; ++reg) {
      float t = fmaxf(fmaxf(s[0][reg], s[1][reg]), fmaxf(s[2][reg], s[3][reg]));
#pragma unroll
      for (int off = 1; off < 16; off <<= 1) t = fmaxf(t, __shfl_xor(t, off));
      const float nm = fmaxf(m[reg], t);
      f[reg] = __expf(m[reg] - nm);
      m[reg] = nm;
    }
    float rs[4] = {0.f, 0.f, 0.f, 0.f};
#pragma unroll
    for (int n = 0; n < 4; ++n) {
#pragma unroll
      for (int reg = 0; reg < 4; ++reg) {
        const float p = __expf(s[n][reg] - m[reg]);
        rs[reg] += p;
        Pl[wq][swzA(g * 4 + reg, n * 16 + l16)] = (_Float16)p;
      }
    }
#pragma unroll
    for (int reg = 0; reg < 4; ++reg) {
      float t = rs[reg];
#pragma unroll
      for (int off = 1; off < 16; off <<= 1) t += __shfl_xor(t, off);
      l[reg] = l[reg] * f[reg] + t;
    }
#pragma unroll
    for (int n = 0; n < 4; ++n)
#pragma unroll
      for (int reg = 0; reg < 4; ++reg) oacc[n][reg] *= f[reg];
    // O += P V   (A = Pl row=l16, B = Vt)
#pragma unroll
    for (int ks = 0; ks < 2; ++ks) {
      const f16x8 pa = *(const f16x8*)(Pl[wq] + swzA(l16, ks * 32 + g * 8));
      f16x8 vb[4];
#pragma unroll
      for (int n = 0; n < 4; ++n) vb[n] = *(const f16x8*)(Vt + swzV(n * 16 + l16, ks * 32 + g * 8));
#pragma unroll
      for (int n = 0; n < 4; ++n)
        oacc[n] = __builtin_amdgcn_mfma_f32_16x16x32_f16(pa, vb[n], oacc[n], 0, 0, 0);
    }
  }
#pragma unroll
  for (int n = 0; n < 4; ++n) {
#pragma unroll
    for (int reg = 0; reg < 4; ++reg) {
      const int r = qt * 64 + wq * 16 + g * 4 + reg;
      seq_out[(size_t)(bb * TT + r) * DD + hh * 64 + n * 16 + l16] = oacc[n][reg] / l[reg];
    }
  }
}

// ---------------- build Wmega [1024][4608] = [Wqkv | W1w W2w W1r W2r Wmg 0pad | Wmv] + bias ----------------
__global__ void prep_mega(const float* __restrict__ Wqkv, const float* __restrict__ bqkv,
                          const float* __restrict__ W1w, const float* __restrict__ W2w,
                          const float* __restrict__ W1r, const float* __restrict__ W2r,
                          const float* __restrict__ Wmg, const float* __restrict__ bmg,
                          const float* __restrict__ Wmv, const float* __restrict__ bmv,
                          float* __restrict__ Wm, float* __restrict__ bm) {
  const int col = blockIdx.x * 256 + threadIdx.x;  // 0..4607
  const int row = blockIdx.y;                      // 0..1024 (1024 = bias)
  if (row < 1024) {
    float v;
    if (col < 3072) v = Wqkv[(size_t)row * 3072 + col];
    else if (col < 3136) v = W1w[row * 64 + col - 3072];
    else if (col < 3200) v = W2w[row * 64 + col - 3136];
    else if (col < 3264) v = W1r[row * 64 + col - 3200];
    else if (col < 3328) v = W2r[row * 64 + col - 3264];
    else if (col < 3344) v = Wmg[row * 16 + col - 3328];
    else if (col < 3584) v = 0.f;
    else v = Wmv[(size_t)row * 1024 + col - 3584];
    Wm[(size_t)row * 4608 + col] = v;
  } else {
    float b = 0.f;
    if (col < 3072) b = bqkv[col];
    else if (col >= 3328 && col < 3344) b = bmg[col - 3328];
    else if (col >= 3584) b = bmv[col - 3584];
    bm[col] = b;
  }
}

// ---------------- exterior products -> Jw, rd, gate (reads mega cols 3072..3343) ----------------
static __device__ __forceinline__ void ext6(const float* a, const float* b, float* L) {
  L[0] = a[0] * b[1] - a[1] * b[0];
  L[1] = a[0] * b[2] - a[2] * b[0];
  L[2] = a[0] * b[3] - a[3] * b[0];
  L[3] = a[1] * b[2] - a[2] * b[1];
  L[4] = a[1] * b[3] - a[3] * b[1];
  L[5] = a[2] * b[3] - a[3] * b[2];
  const float n = sqrtf(L[0]*L[0] + L[1]*L[1] + L[2]*L[2] + L[3]*L[3] + L[4]*L[4] + L[5]*L[5]);
  const float s = 1.f / fmaxf(n, 1e-12f);
#pragma unroll
  for (int i = 0; i < 6; ++i) L[i] *= s;
}

__global__ void lines_post(const float* __restrict__ mega, float* __restrict__ jw,
                           float* __restrict__ rdv, float* __restrict__ gate) {
  const int idx = blockIdx.x * 256 + threadIdx.x;  // (b*T+t)*16 + h
  const int h = idx & 15;
  const int bt = idx >> 4;
  const int t = bt & 1023;
  const int b = bt >> 10;
  const float* row = mega + (size_t)bt * QS + 3072;
  float w1[4] = {0.f, 0.f, 0.f, 0.f}, w2[4], r1[4], r2[4];
  if (t > 0) {
#pragma unroll
    for (int i = 0; i < 4; ++i) w1[i] = row[-QS + h * 4 + i];
  }
#pragma unroll
  for (int i = 0; i < 4; ++i) {
    w2[i] = row[64 + h * 4 + i];
    r1[i] = row[128 + h * 4 + i];
    r2[i] = row[192 + h * 4 + i];
  }
  const float gp = row[256 + h];
  float wl[6], rl[6];
  ext6(w1, w2, wl);
  ext6(r1, r2, rl);
  const size_t o = ((size_t)(b * 16 + h) * 1024 + t) * 6;
  jw[o + 0] =  wl[5]; jw[o + 1] = -wl[4]; jw[o + 2] =  wl[3];
  jw[o + 3] =  wl[2]; jw[o + 4] = -wl[1]; jw[o + 5] =  wl[0];
#pragma unroll
  for (int i = 0; i < 6; ++i) rdv[o + i] = rl[i];
  gate[idx] = 1.f / (1.f + __expf(-gp));
}

// ---------------- Gram memory scan: one wave per (b,h) ----------------
__global__ __launch_bounds__(64) void gram_scan(const float* __restrict__ jwv,
    const float* __restrict__ rdv, const float* __restrict__ decay_logits,
    const float* __restrict__ iter_mix, float* __restrict__ mem_score) {
  const int h = blockIdx.x & 15, b = blockIdx.x >> 4;
  const int lane = threadIdx.x;
  const float decay = 1.f / (1.f + __expf(-decay_logits[h]));
  const float alpha = 1.f / (1.f + __expf(-iter_mix[0]));
  __shared__ float jws[64][8], rds[64][8];
  const size_t base = (size_t)(b * 16 + h) * 1024 * 6;
  const int j = lane & 7;
  float Mc[6] = {0.f, 0.f, 0.f, 0.f, 0.f, 0.f};
  for (int ttile = 0; ttile < 16; ++ttile) {
    __syncthreads();
    {
      const size_t t6 = base + (size_t)(ttile * 64 + lane) * 6;
#pragma unroll
      for (int i = 0; i < 6; ++i) { jws[lane][i] = jwv[t6 + i]; rds[lane][i] = rdv[t6 + i]; }
      jws[lane][6] = 0.f; jws[lane][7] = 0.f; rds[lane][6] = 0.f; rds[lane][7] = 0.f;
    }
    __syncthreads();
    for (int tl = 0; tl < 64; ++tl) {
      float jv[6], rv[6];
#pragma unroll
      for (int i = 0; i < 6; ++i) { jv[i] = jws[tl][i]; rv[i] = rds[tl][i]; }
      const float jj = jws[tl][j];
      const float rj = rds[tl][j];
      float rdM = 0.f;
#pragma unroll
      for (int i = 0; i < 6; ++i) rdM += rv[i] * Mc[i];
      float s1 = rdM * rj, s2 = rdM * rdM;
      s1 += __shfl_xor(s1, 1, 8); s1 += __shfl_xor(s1, 2, 8); s1 += __shfl_xor(s1, 4, 8);
      s2 += __shfl_xor(s2, 1, 8); s2 += __shfl_xor(s2, 2, 8); s2 += __shfl_xor(s2, 4, 8);
      if (lane == 0)
        mem_score[(size_t)(b * 16 + h) * 1024 + ttile * 64 + tl] = (1.f - alpha) * s1 + alpha * s2;
#pragma unroll
      for (int i = 0; i < 6; ++i) Mc[i] = decay * (Mc[i] + jv[i] * jj);
    }
  }
}

// ---------------- gated mean over heads ----------------
__global__ void gmean_kernel(const float* __restrict__ ms, const float* __restrict__ gate,
    const float* __restrict__ mem_scale, float* __restrict__ gm) {
  const int bt = blockIdx.x * 256 + threadIdx.x;  // 0..2047
  const int b = bt >> 10, t = bt & 1023;
  float acc = 0.f;
#pragma unroll
  for (int h = 0; h < 16; ++h) {
    const float sc = ms[(size_t)(b * 16 + h) * 1024 + t];
    const float gt = gate[(size_t)bt * 16 + h];
    acc += (1.f / (1.f + __expf(-sc * mem_scale[h]))) * gt;
  }
  gm[bt] = acc * (1.f / 16.f);
}

// ---------------- attnin = seq_out + gmean * mem_val (mv lives in mega cols 3584..4607) ----------------
__global__ void combine_kernel(const float* __restrict__ seq, const float* __restrict__ mega,
    const float* __restrict__ gm, float* __restrict__ outp) {
  const int i = blockIdx.x * 256 + threadIdx.x;  // float4 index, 524288 total
  const int bt = i >> 8, c4 = i & 255;
  const float g = gm[bt];
  const float4 s4 = *(const float4*)(seq + (size_t)i * 4);
  const float4 m4 = *(const float4*)(mega + (size_t)bt * QS + 3584 + c4 * 4);
  float4 o;
  o.x = s4.x + g * m4.x;
  o.y = s4.y + g * m4.y;
  o.z = s4.z + g * m4.z;
  o.w = s4.w + g * m4.w;
  *(float4*)(outp + (size_t)i * 4) = o;
}

extern "C" void kernel_launch(void* const* d_in, const int* in_sizes, int n_in,
                              void* d_out, int out_size, void* d_ws, size_t ws_size,
                              hipStream_t stream) {
  (void)in_sizes; (void)n_in; (void)out_size; (void)ws_size;
  const float* x       = (const float*)d_in[0];
  const float* ln1_g   = (const float*)d_in[1];
  const float* ln1_b   = (const float*)d_in[2];
  const float* Wqkv    = (const float*)d_in[3];
  const float* bqkv    = (const float*)d_in[4];
  const float* W1w     = (const float*)d_in[5];
  const float* W2w     = (const float*)d_in[6];
  const float* W1r     = (const float*)d_in[7];
  const float* W2r     = (const float*)d_in[8];
  const float* Wmv     = (const float*)d_in[9];
  const float* bmv     = (const float*)d_in[10];
  const float* Wmg     = (const float*)d_in[11];
  const float* bmg     = (const float*)d_in[12];
  const float* mscale  = (const float*)d_in[13];
  const float* itermix = (const float*)d_in[14];
  const float* dlogits = (const float*)d_in[15];
  const float* Wout    = (const float*)d_in[16];
  const float* bout    = (const float*)d_in[17];
  const float* ln2_g   = (const float*)d_in[18];
  const float* ln2_b   = (const float*)d_in[19];
  const float* Wfc     = (const float*)d_in[20];
  const float* bfc     = (const float*)d_in[21];
  const float* Wproj   = (const float*)d_in[22];
  const float* bproj   = (const float*)d_in[23];
  float* out = (float*)d_out;
  float* ws = (float*)d_ws;

  const size_t M1 = 1u << 20;
  float* h    = ws;                        // 2M  (h -> attnin -> h2)
  float* mega = ws + 2 * M1;               // 9M  (2048 x 4608); fc reuses 2M..10M later
  float* fc   = ws + 2 * M1;               // 8M
  float* Wm   = ws + 11 * M1;              // 4.5M [dead after mega GEMM]
  float* bm   = ws + 11 * M1 + 4718592;    // 4608 [dead after mega GEMM]
  float* seq  = ws + 11 * M1;              // 2M  (written post-mega-GEMM, overlaps Wm)
  float* y    = ws + 13 * M1;              // 2M  (overlaps Wm tail)
  float* jw   = ws + 15 * M1;              // 196608
  float* rd   = ws + 15 * M1 + 196608;     // 196608
  float* gate = ws + 15 * M1 + 393216;     // 32768
  float* ms   = ws + 15 * M1 + 425984;     // 32768
  float* gm   = ws + 15 * M1 + 458752;     // 2048

  prep_mega<<<dim3(18, 1025), 256, 0, stream>>>(Wqkv, bqkv, W1w, W2w, W1r, W2r,
                                                Wmg, bmg, Wmv, bmv, Wm, bm);
  ln_kernel<<<2048, 256, 0, stream>>>(x, ln1_g, ln1_b, h);
  gemm_f16<<<dim3(36, 16), 256, 0, stream>>>(h, Wm, bm, nullptr, mega, 2048, 4608, 1024, 0);
  attn_mfma<<<dim3(16, 16, 2), 256, 0, stream>>>(mega, seq);
  lines_post<<<128, 256, 0, stream>>>(mega, jw, rd, gate);
  gram_scan<<<32, 64, 0, stream>>>(jw, rd, dlogits, itermix, ms);
  gmean_kernel<<<8, 256, 0, stream>>>(ms, gate, mscale, gm);
  combine_kernel<<<2048, 256, 0, stream>>>(seq, mega, gm, h);
  gemm_f16<<<dim3(8, 16), 256, 0, stream>>>(h, Wout, bout, x, y, 2048, 1024, 1024, 0);
  ln_kernel<<<2048, 256, 0, stream>>>(y, ln2_g, ln2_b, h);
  gemm_f16<<<dim3(32, 16), 256, 0, stream>>>(h, Wfc, bfc, nullptr, fc, 2048, 4096, 1024, 1);
  gemm_f16<<<dim3(8, 16), 256, 0, stream>>>(fc, Wproj, bproj, y, out, 2048, 1024, 4096, 0);
}

// Round 3
// 388.904 us; speedup vs baseline: 2.3718x; 1.4913x over previous
//
#include <hip/hip_runtime.h>
#include <hip/hip_bf16.h>
#include <math.h>

typedef float f32x4 __attribute__((ext_vector_type(4)));
typedef _Float16 f16x8 __attribute__((ext_vector_type(8)));
typedef _Float16 f16x4 __attribute__((ext_vector_type(4)));

#define TT 1024
#define DD 1024
#define QS 4608   // mega GEMM output row stride: [qkv 3072 | lines 512 | mv 1024]

// ---------------- generic f16-MFMA GEMM: C = A(MxK) @ B(KxN) + bias [+res] [+gelu] ----------------
static __device__ __forceinline__ int swz(int row, int k) {
  return row * 32 + (((k >> 3) ^ ((row >> 1) & 3)) << 3) + (k & 7);
}

__global__ __launch_bounds__(256) void gemm_f16(
    const float* __restrict__ A, const float* __restrict__ B,
    const float* __restrict__ bias, const float* __restrict__ residual,
    float* __restrict__ C, int M, int N, int K, int act) {
  __shared__ __align__(16) _Float16 As[128 * 32];
  __shared__ __align__(16) _Float16 Bs[128 * 32];
  const int tid = threadIdx.x;
  const int lane = tid & 63;
  const int wid = tid >> 6;
  const int wr = wid >> 1, wc = wid & 1;           // 2x2 waves over 128x128
  const int g = lane >> 4, l16 = lane & 15;
  const int row0 = blockIdx.y * 128, col0 = blockIdx.x * 128;

  f32x4 acc[4][4];
#pragma unroll
  for (int m = 0; m < 4; ++m)
#pragma unroll
    for (int n = 0; n < 4; ++n) acc[m][n] = (f32x4){0.f, 0.f, 0.f, 0.f};

  const int ar = tid >> 1, ah = tid & 1;           // A stage: row, k-half
  const int bn = tid & 127, bg = (tid >> 7) * 2;   // B stage: col, k-octet base

  for (int k0 = 0; k0 < K; k0 += 32) {
#pragma unroll
    for (int t2 = 0; t2 < 2; ++t2) {
      const int gk = ah * 2 + t2;
      const float* ap = A + (size_t)(row0 + ar) * K + k0 + gk * 8;
      const float4 a0 = *(const float4*)ap;
      const float4 a1 = *(const float4*)(ap + 4);
      f16x8 pk;
      pk[0] = (_Float16)a0.x; pk[1] = (_Float16)a0.y; pk[2] = (_Float16)a0.z; pk[3] = (_Float16)a0.w;
      pk[4] = (_Float16)a1.x; pk[5] = (_Float16)a1.y; pk[6] = (_Float16)a1.z; pk[7] = (_Float16)a1.w;
      *(f16x8*)(As + swz(ar, gk * 8)) = pk;
    }
#pragma unroll
    for (int t2 = 0; t2 < 2; ++t2) {
      const int gk = bg + t2;
      const float* bp = B + (size_t)(k0 + gk * 8) * N + col0 + bn;
      f16x8 pk;
#pragma unroll
      for (int m2 = 0; m2 < 8; ++m2) pk[m2] = (_Float16)bp[(size_t)m2 * N];
      *(f16x8*)(Bs + swz(bn, gk * 8)) = pk;
    }
    __syncthreads();
    f16x8 af[4], bfv[4];
#pragma unroll
    for (int m = 0; m < 4; ++m) af[m] = *(const f16x8*)(As + swz(wr * 64 + m * 16 + l16, g * 8));
#pragma unroll
    for (int n = 0; n < 4; ++n) bfv[n] = *(const f16x8*)(Bs + swz(wc * 64 + n * 16 + l16, g * 8));
#pragma unroll
    for (int m = 0; m < 4; ++m)
#pragma unroll
      for (int n = 0; n < 4; ++n)
        acc[m][n] = __builtin_amdgcn_mfma_f32_16x16x32_f16(af[m], bfv[n], acc[m][n], 0, 0, 0);
    __syncthreads();
  }
#pragma unroll
  for (int m = 0; m < 4; ++m) {
#pragma unroll
    for (int n = 0; n < 4; ++n) {
      const int col = col0 + wc * 64 + n * 16 + l16;
      const float bv = bias ? bias[col] : 0.f;
#pragma unroll
      for (int rg = 0; rg < 4; ++rg) {
        const int row = row0 + wr * 64 + m * 16 + g * 4 + rg;
        const size_t off = (size_t)row * N + col;
        float v = acc[m][n][rg] + bv;
        if (residual) v += residual[off];
        if (act == 1) v = 0.5f * v * (1.f + erff(v * 0.70710678118654752f));
        C[off] = v;
      }
    }
  }
}

// ---------------- LayerNorm over D=1024, one row per 256-thread block ----------------
__global__ __launch_bounds__(256) void ln_kernel(const float* __restrict__ in,
    const float* __restrict__ gw, const float* __restrict__ bw, float* __restrict__ out) {
  const int row = blockIdx.x, tid = threadIdx.x;
  const float* x = in + (size_t)row * DD;
  const float4 v = *(const float4*)(x + tid * 4);
  float s = v.x + v.y + v.z + v.w;
  float sq = v.x * v.x + v.y * v.y + v.z * v.z + v.w * v.w;
#pragma unroll
  for (int off = 32; off >= 1; off >>= 1) { s += __shfl_xor(s, off); sq += __shfl_xor(sq, off); }
  __shared__ float red[8];
  const int lane = tid & 63, wv = tid >> 6;
  if (lane == 0) { red[wv] = s; red[4 + wv] = sq; }
  __syncthreads();
  s = red[0] + red[1] + red[2] + red[3];
  sq = red[4] + red[5] + red[6] + red[7];
  const float mean = s * (1.f / 1024.f);
  const float var = sq * (1.f / 1024.f) - mean * mean;
  const float rstd = rsqrtf(var + 1e-5f);
  const float4 g4 = *(const float4*)(gw + tid * 4);
  const float4 b4 = *(const float4*)(bw + tid * 4);
  float4 o;
  o.x = (v.x - mean) * rstd * g4.x + b4.x;
  o.y = (v.y - mean) * rstd * g4.y + b4.y;
  o.z = (v.z - mean) * rstd * g4.z + b4.z;
  o.w = (v.w - mean) * rstd * g4.w + b4.w;
  *(float4*)(out + (size_t)row * DD + tid * 4) = o;
}

// ---------------- MFMA f16 causal flash attention ----------------
static __device__ __forceinline__ int swzA(int row, int k) {
  return row * 64 + ((((k >> 3) ^ row) & 7) << 3) + (k & 7);
}
static __device__ __forceinline__ int swzV(int row, int k) {
  return row * 64 + ((((k >> 3) ^ row ^ (row >> 3)) & 7) << 3) + (k & 7);
}

__global__ __launch_bounds__(256) void attn_mfma(const float* __restrict__ qkv,
                                                 float* __restrict__ seq_out) {
  __shared__ __align__(16) _Float16 Kl[64 * 64];
  __shared__ __align__(16) _Float16 Vt[64 * 64];
  __shared__ __align__(16) _Float16 Pl[4][16 * 64];
  const int tid = threadIdx.x, lane = tid & 63, wq = tid >> 6;
  const int g = lane >> 4, l16 = lane & 15;
  const int qt = blockIdx.x, hh = blockIdx.y, bb = blockIdx.z;
  const int nt = qt + 1;

  f16x8 qf[2];
  {
    const float* qp = qkv + (size_t)(bb * TT + qt * 64 + wq * 16 + l16) * QS + hh * 64;
#pragma unroll
    for (int ks = 0; ks < 2; ++ks) {
      const float4 a0 = *(const float4*)(qp + ks * 32 + g * 8);
      const float4 a1 = *(const float4*)(qp + ks * 32 + g * 8 + 4);
      qf[ks][0] = (_Float16)(a0.x * 0.125f); qf[ks][1] = (_Float16)(a0.y * 0.125f);
      qf[ks][2] = (_Float16)(a0.z * 0.125f); qf[ks][3] = (_Float16)(a0.w * 0.125f);
      qf[ks][4] = (_Float16)(a1.x * 0.125f); qf[ks][5] = (_Float16)(a1.y * 0.125f);
      qf[ks][6] = (_Float16)(a1.z * 0.125f); qf[ks][7] = (_Float16)(a1.w * 0.125f);
    }
  }

  f32x4 oacc[4];
#pragma unroll
  for (int n = 0; n < 4; ++n) oacc[n] = (f32x4){0.f, 0.f, 0.f, 0.f};
  float m[4] = {-INFINITY, -INFINITY, -INFINITY, -INFINITY};
  float l[4] = {0.f, 0.f, 0.f, 0.f};

  const int skey = tid >> 2, sc4 = tid & 3;

  for (int tt = 0; tt < nt; ++tt) {
    if (tt) __syncthreads();
    {
      const float* kp = qkv + (size_t)(bb * TT + tt * 64 + skey) * QS + hh * 64 + 1024;
      const float* vp = kp + 1024;
#pragma unroll
      for (int ii = 0; ii < 4; ++ii) {
        const int d0 = sc4 * 4 + ii * 16;
        const float4 kv = *(const float4*)(kp + d0);
        f16x4 k4;
        k4[0] = (_Float16)kv.x; k4[1] = (_Float16)kv.y; k4[2] = (_Float16)kv.z; k4[3] = (_Float16)kv.w;
        *(f16x4*)(Kl + swzA(skey, d0)) = k4;
        const float4 vv = *(const float4*)(vp + d0);
        Vt[swzV(d0 + 0, skey)] = (_Float16)vv.x;
        Vt[swzV(d0 + 1, skey)] = (_Float16)vv.y;
        Vt[swzV(d0 + 2, skey)] = (_Float16)vv.z;
        Vt[swzV(d0 + 3, skey)] = (_Float16)vv.w;
      }
    }
    __syncthreads();
    f32x4 s[4];
#pragma unroll
    for (int n = 0; n < 4; ++n) s[n] = (f32x4){0.f, 0.f, 0.f, 0.f};
#pragma unroll
    for (int ks = 0; ks < 2; ++ks) {
      f16x8 kf[4];
#pragma unroll
      for (int n = 0; n < 4; ++n) kf[n] = *(const f16x8*)(Kl + swzA(n * 16 + l16, ks * 32 + g * 8));
#pragma unroll
      for (int n = 0; n < 4; ++n)
        s[n] = __builtin_amdgcn_mfma_f32_16x16x32_f16(qf[ks], kf[n], s[n], 0, 0, 0);
    }
    if (tt == qt) {
      const int rloc = wq * 16 + g * 4;
#pragma unroll
      for (int n = 0; n < 4; ++n) {
        const int cloc = n * 16 + l16;
#pragma unroll
        for (int reg = 0; reg < 4; ++reg)
          if (cloc > rloc + reg) s[n][reg] = -INFINITY;
      }
    }
    float f[4];
#pragma unroll
    for (int reg = 0; reg < 4; ++reg) {
      float t = fmaxf(fmaxf(s[0][reg], s[1][reg]), fmaxf(s[2][reg], s[3][reg]));
#pragma unroll
      for (int off = 1; off < 16; off <<= 1) t = fmaxf(t, __shfl_xor(t, off));
      const float nm = fmaxf(m[reg], t);
      f[reg] = __expf(m[reg] - nm);
      m[reg] = nm;
    }
    float rs[4] = {0.f, 0.f, 0.f, 0.f};
#pragma unroll
    for (int n = 0; n < 4; ++n) {
#pragma unroll
      for (int reg = 0; reg < 4; ++reg) {
        const float p = __expf(s[n][reg] - m[reg]);
        rs[reg] += p;
        Pl[wq][swzA(g * 4 + reg, n * 16 + l16)] = (_Float16)p;
      }
    }
#pragma unroll
    for (int reg = 0; reg < 4; ++reg) {
      float t = rs[reg];
#pragma unroll
      for (int off = 1; off < 16; off <<= 1) t += __shfl_xor(t, off);
      l[reg] = l[reg] * f[reg] + t;
    }
#pragma unroll
    for (int n = 0; n < 4; ++n)
#pragma unroll
      for (int reg = 0; reg < 4; ++reg) oacc[n][reg] *= f[reg];
#pragma unroll
    for (int ks = 0; ks < 2; ++ks) {
      const f16x8 pa = *(const f16x8*)(Pl[wq] + swzA(l16, ks * 32 + g * 8));
      f16x8 vb[4];
#pragma unroll
      for (int n = 0; n < 4; ++n) vb[n] = *(const f16x8*)(Vt + swzV(n * 16 + l16, ks * 32 + g * 8));
#pragma unroll
      for (int n = 0; n < 4; ++n)
        oacc[n] = __builtin_amdgcn_mfma_f32_16x16x32_f16(pa, vb[n], oacc[n], 0, 0, 0);
    }
  }
#pragma unroll
  for (int n = 0; n < 4; ++n) {
#pragma unroll
    for (int reg = 0; reg < 4; ++reg) {
      const int r = qt * 64 + wq * 16 + g * 4 + reg;
      seq_out[(size_t)(bb * TT + r) * DD + hh * 64 + n * 16 + l16] = oacc[n][reg] / l[reg];
    }
  }
}

// ---------------- build Wmega [1024][4608] ----------------
__global__ void prep_mega(const float* __restrict__ Wqkv, const float* __restrict__ bqkv,
                          const float* __restrict__ W1w, const float* __restrict__ W2w,
                          const float* __restrict__ W1r, const float* __restrict__ W2r,
                          const float* __restrict__ Wmg, const float* __restrict__ bmg,
                          const float* __restrict__ Wmv, const float* __restrict__ bmv,
                          float* __restrict__ Wm, float* __restrict__ bm) {
  const int col = blockIdx.x * 256 + threadIdx.x;  // 0..4607
  const int row = blockIdx.y;                      // 0..1024 (1024 = bias)
  if (row < 1024) {
    float v;
    if (col < 3072) v = Wqkv[(size_t)row * 3072 + col];
    else if (col < 3136) v = W1w[row * 64 + col - 3072];
    else if (col < 3200) v = W2w[row * 64 + col - 3136];
    else if (col < 3264) v = W1r[row * 64 + col - 3200];
    else if (col < 3328) v = W2r[row * 64 + col - 3264];
    else if (col < 3344) v = Wmg[row * 16 + col - 3328];
    else if (col < 3584) v = 0.f;
    else v = Wmv[(size_t)row * 1024 + col - 3584];
    Wm[(size_t)row * 4608 + col] = v;
  } else {
    float b = 0.f;
    if (col < 3072) b = bqkv[col];
    else if (col >= 3328 && col < 3344) b = bmg[col - 3328];
    else if (col >= 3584) b = bmv[col - 3584];
    bm[col] = b;
  }
}

// ---------------- exterior products -> Jw, rd, gate ----------------
static __device__ __forceinline__ void ext6(const float* a, const float* b, float* L) {
  L[0] = a[0] * b[1] - a[1] * b[0];
  L[1] = a[0] * b[2] - a[2] * b[0];
  L[2] = a[0] * b[3] - a[3] * b[0];
  L[3] = a[1] * b[2] - a[2] * b[1];
  L[4] = a[1] * b[3] - a[3] * b[1];
  L[5] = a[2] * b[3] - a[3] * b[2];
  const float n = sqrtf(L[0]*L[0] + L[1]*L[1] + L[2]*L[2] + L[3]*L[3] + L[4]*L[4] + L[5]*L[5]);
  const float s = 1.f / fmaxf(n, 1e-12f);
#pragma unroll
  for (int i = 0; i < 6; ++i) L[i] *= s;
}

__global__ void lines_post(const float* __restrict__ mega, float* __restrict__ jw,
                           float* __restrict__ rdv, float* __restrict__ gate) {
  const int idx = blockIdx.x * 256 + threadIdx.x;  // (b*T+t)*16 + h
  const int h = idx & 15;
  const int bt = idx >> 4;
  const int t = bt & 1023;
  const int b = bt >> 10;
  const float* row = mega + (size_t)bt * QS + 3072;
  float w1[4] = {0.f, 0.f, 0.f, 0.f}, w2[4], r1[4], r2[4];
  if (t > 0) {
#pragma unroll
    for (int i = 0; i < 4; ++i) w1[i] = row[-QS + h * 4 + i];
  }
#pragma unroll
  for (int i = 0; i < 4; ++i) {
    w2[i] = row[64 + h * 4 + i];
    r1[i] = row[128 + h * 4 + i];
    r2[i] = row[192 + h * 4 + i];
  }
  const float gp = row[256 + h];
  float wl[6], rl[6];
  ext6(w1, w2, wl);
  ext6(r1, r2, rl);
  const size_t o = ((size_t)(b * 16 + h) * 1024 + t) * 6;
  jw[o + 0] =  wl[5]; jw[o + 1] = -wl[4]; jw[o + 2] =  wl[3];
  jw[o + 3] =  wl[2]; jw[o + 4] = -wl[1]; jw[o + 5] =  wl[0];
#pragma unroll
  for (int i = 0; i < 6; ++i) rdv[o + i] = rl[i];
  gate[idx] = 1.f / (1.f + __expf(-gp));
}

// ---------------- chunk-parallel Gram scan ----------------
// One wave per (b,h). Lane L owns timesteps [16L, 16L+16). M symmetric: 21 regs.
// midx(i,j) for i<=j: i*(13-i)/2 + (j-i)
static __device__ __forceinline__ int midx(int i, int j) {
  return (i <= j) ? (i * (13 - i)) / 2 + (j - i) : (j * (13 - j)) / 2 + (i - j);
}

__global__ __launch_bounds__(64) void gram_scan(const float* __restrict__ jwv,
    const float* __restrict__ rdv, const float* __restrict__ decay_logits,
    const float* __restrict__ iter_mix, float* __restrict__ mem_score) {
  const int h = blockIdx.x & 15, b = blockIdx.x >> 4;
  const int lane = threadIdx.x;
  const float decay = 1.f / (1.f + __expf(-decay_logits[h]));
  const float alpha = 1.f / (1.f + __expf(-iter_mix[0]));
  // lane-private LDS segments, 193-float stride => bank = (lane + off) % 32, 2-way free
  __shared__ float sd[64 * 193];
  const size_t base = (size_t)(b * 16 + h) * 1024 * 6;
  // stage J and r (coalesced global reads -> lane-private segments)
  for (int it = 0; it < 96; ++it) {
    const int idx = it * 64 + lane;          // 0..6143
    const int t = idx / 6, i = idx - 6 * t;
    const int ld = t >> 4, s = t & 15;
    sd[ld * 193 + s * 6 + i] = jwv[base + idx];
    sd[ld * 193 + 96 + s * 6 + i] = rdv[base + idx];
  }
  __syncthreads();
  const float* seg = sd + lane * 193;

  // phase 1: end-anchored chunk summary C = sum_t d^(end-t) J_t J_t^T
  float C[21];
#pragma unroll
  for (int e = 0; e < 21; ++e) C[e] = 0.f;
  for (int s = 0; s < 16; ++s) {
    float J[6], dJ[6];
#pragma unroll
    for (int i = 0; i < 6; ++i) { J[i] = seg[s * 6 + i]; dJ[i] = decay * J[i]; }
#pragma unroll
    for (int i = 0; i < 6; ++i)
#pragma unroll
      for (int j = i; j < 6; ++j)
        C[midx(i, j)] = decay * C[midx(i, j)] + dJ[i] * J[j];
  }
  // phase 2: Hillis-Steele inclusive scan across lanes with factor d^(16*2^k), then shift
  const float d2 = decay * decay, d4 = d2 * d2, d8 = d4 * d4;
  float fk = d8 * d8;  // d^16
#pragma unroll
  for (int k = 0; k < 6; ++k) {
    const int off = 1 << k;
#pragma unroll
    for (int e = 0; e < 21; ++e) {
      const float u = __shfl(C[e], lane - off);
      if (lane >= off) C[e] += fk * u;
    }
    fk = fk * fk;
  }
  float M[21];
#pragma unroll
  for (int e = 0; e < 21; ++e) {
    const float u = __shfl(C[e], lane - 1);
    M[e] = (lane >= 1) ? u : 0.f;
  }
  // phase 3: re-run chunk computing scores (state BEFORE update = strictly past)
  float* msp = mem_score + (size_t)(b * 16 + h) * 1024 + lane * 16;
  for (int s = 0; s < 16; ++s) {
    float J[6], r[6];
#pragma unroll
    for (int i = 0; i < 6; ++i) { J[i] = seg[s * 6 + i]; r[i] = seg[96 + s * 6 + i]; }
    float rdM[6];
#pragma unroll
    for (int i = 0; i < 6; ++i) {
      float a = 0.f;
#pragma unroll
      for (int j = 0; j < 6; ++j) a += M[midx(i, j)] * r[j];
      rdM[i] = a;
    }
    float s1 = 0.f, s2 = 0.f;
#pragma unroll
    for (int i = 0; i < 6; ++i) { s1 += rdM[i] * r[i]; s2 += rdM[i] * rdM[i]; }
    msp[s] = (1.f - alpha) * s1 + alpha * s2;
    float dJ[6];
#pragma unroll
    for (int i = 0; i < 6; ++i) dJ[i] = decay * J[i];
#pragma unroll
    for (int i = 0; i < 6; ++i)
#pragma unroll
      for (int j = i; j < 6; ++j)
        M[midx(i, j)] = decay * M[midx(i, j)] + dJ[i] * J[j];
  }
}

// ---------------- gated mean over heads ----------------
__global__ void gmean_kernel(const float* __restrict__ ms, const float* __restrict__ gate,
    const float* __restrict__ mem_scale, float* __restrict__ gm) {
  const int bt = blockIdx.x * 256 + threadIdx.x;  // 0..2047
  const int b = bt >> 10, t = bt & 1023;
  float acc = 0.f;
#pragma unroll
  for (int h = 0; h < 16; ++h) {
    const float sc = ms[(size_t)(b * 16 + h) * 1024 + t];
    const float gt = gate[(size_t)bt * 16 + h];
    acc += (1.f / (1.f + __expf(-sc * mem_scale[h]))) * gt;
  }
  gm[bt] = acc * (1.f / 16.f);
}

// ---------------- attnin = seq_out + gmean * mem_val ----------------
__global__ void combine_kernel(const float* __restrict__ seq, const float* __restrict__ mega,
    const float* __restrict__ gm, float* __restrict__ outp) {
  const int i = blockIdx.x * 256 + threadIdx.x;  // float4 index, 524288 total
  const int bt = i >> 8, c4 = i & 255;
  const float g = gm[bt];
  const float4 s4 = *(const float4*)(seq + (size_t)i * 4);
  const float4 m4 = *(const float4*)(mega + (size_t)bt * QS + 3584 + c4 * 4);
  float4 o;
  o.x = s4.x + g * m4.x;
  o.y = s4.y + g * m4.y;
  o.z = s4.z + g * m4.z;
  o.w = s4.w + g * m4.w;
  *(float4*)(outp + (size_t)i * 4) = o;
}

extern "C" void kernel_launch(void* const* d_in, const int* in_sizes, int n_in,
                              void* d_out, int out_size, void* d_ws, size_t ws_size,
                              hipStream_t stream) {
  (void)in_sizes; (void)n_in; (void)out_size; (void)ws_size;
  const float* x       = (const float*)d_in[0];
  const float* ln1_g   = (const float*)d_in[1];
  const float* ln1_b   = (const float*)d_in[2];
  const float* Wqkv    = (const float*)d_in[3];
  const float* bqkv    = (const float*)d_in[4];
  const float* W1w     = (const float*)d_in[5];
  const float* W2w     = (const float*)d_in[6];
  const float* W1r     = (const float*)d_in[7];
  const float* W2r     = (const float*)d_in[8];
  const float* Wmv     = (const float*)d_in[9];
  const float* bmv     = (const float*)d_in[10];
  const float* Wmg     = (const float*)d_in[11];
  const float* bmg     = (const float*)d_in[12];
  const float* mscale  = (const float*)d_in[13];
  const float* itermix = (const float*)d_in[14];
  const float* dlogits = (const float*)d_in[15];
  const float* Wout    = (const float*)d_in[16];
  const float* bout    = (const float*)d_in[17];
  const float* ln2_g   = (const float*)d_in[18];
  const float* ln2_b   = (const float*)d_in[19];
  const float* Wfc     = (const float*)d_in[20];
  const float* bfc     = (const float*)d_in[21];
  const float* Wproj   = (const float*)d_in[22];
  const float* bproj   = (const float*)d_in[23];
  float* out = (float*)d_out;
  float* ws = (float*)d_ws;

  const size_t M1 = 1u << 20;
  float* h    = ws;                        // 2M  (h -> attnin -> h2)
  float* mega = ws + 2 * M1;               // 9M  (2048 x 4608); fc reuses 2M..10M later
  float* fc   = ws + 2 * M1;               // 8M
  float* Wm   = ws + 11 * M1;              // 4.5M [dead after mega GEMM]
  float* bm   = ws + 11 * M1 + 4718592;    // 4608 [dead after mega GEMM]
  float* seq  = ws + 11 * M1;              // 2M  (written post-mega-GEMM, overlaps Wm)
  float* y    = ws + 13 * M1;              // 2M  (overlaps Wm tail)
  float* jw   = ws + 15 * M1;              // 196608
  float* rd   = ws + 15 * M1 + 196608;     // 196608
  float* gate = ws + 15 * M1 + 393216;     // 32768
  float* ms   = ws + 15 * M1 + 425984;     // 32768
  float* gm   = ws + 15 * M1 + 458752;     // 2048

  prep_mega<<<dim3(18, 1025), 256, 0, stream>>>(Wqkv, bqkv, W1w, W2w, W1r, W2r,
                                                Wmg, bmg, Wmv, bmv, Wm, bm);
  ln_kernel<<<2048, 256, 0, stream>>>(x, ln1_g, ln1_b, h);
  gemm_f16<<<dim3(36, 16), 256, 0, stream>>>(h, Wm, bm, nullptr, mega, 2048, 4608, 1024, 0);
  attn_mfma<<<dim3(16, 16, 2), 256, 0, stream>>>(mega, seq);
  lines_post<<<128, 256, 0, stream>>>(mega, jw, rd, gate);
  gram_scan<<<32, 64, 0, stream>>>(jw, rd, dlogits, itermix, ms);
  gmean_kernel<<<8, 256, 0, stream>>>(ms, gate, mscale, gm);
  combine_kernel<<<2048, 256, 0, stream>>>(seq, mega, gm, h);
  gemm_f16<<<dim3(8, 16), 256, 0, stream>>>(h, Wout, bout, x, y, 2048, 1024, 1024, 0);
  ln_kernel<<<2048, 256, 0, stream>>>(y, ln2_g, ln2_b, h);
  gemm_f16<<<dim3(32, 16), 256, 0, stream>>>(h, Wfc, bfc, nullptr, fc, 2048, 4096, 1024, 1);
  gemm_f16<<<dim3(8, 16), 256, 0, stream>>>(fc, Wproj, bproj, y, out, 2048, 1024, 4096, 0);
}

// Round 4
// 301.979 us; speedup vs baseline: 3.0545x; 1.2879x over previous
//
#include <hip/hip_runtime.h>
#include <hip/hip_bf16.h>
#include <math.h>

typedef float f32x4 __attribute__((ext_vector_type(4)));
typedef _Float16 f16x8 __attribute__((ext_vector_type(8)));
typedef _Float16 f16x4 __attribute__((ext_vector_type(4)));

#define TT 1024
#define DD 1024
#define QS 4608   // mega GEMM output row stride: [qkv 3072 | lines 512 | mv 1024]

// ---------------- shared helpers ----------------
static __device__ __forceinline__ int swz(int row, int k) {
  return row * 32 + (((k >> 3) ^ ((row >> 1) & 3)) << 3) + (k & 7);
}

// ---------------- generic f16-MFMA GEMM (direct store) ----------------
// 1D grid (XCD-swizzled), 128x128 tile, 2-phase pipelined reg staging.
__global__ __launch_bounds__(256) void gemm_f16(
    const float* __restrict__ A, const float* __restrict__ B,
    const float* __restrict__ bias, const float* __restrict__ residual,
    void* __restrict__ Cv, int M, int N, int K, int act, int gx, int store16) {
  __shared__ __align__(16) _Float16 As[128 * 32];
  __shared__ __align__(16) _Float16 Bs[128 * 32];
  const int tid = threadIdx.x;
  const int lane = tid & 63;
  const int wid = tid >> 6;
  const int wr = wid >> 1, wc = wid & 1;
  const int g = lane >> 4, l16 = lane & 15;
  const int cpx = gridDim.x >> 3;
  const int wg = (blockIdx.x & 7) * cpx + (blockIdx.x >> 3);
  const int row0 = (wg / gx) * 128, col0 = (wg % gx) * 128;

  f32x4 acc[4][4];
#pragma unroll
  for (int m = 0; m < 4; ++m)
#pragma unroll
    for (int n = 0; n < 4; ++n) acc[m][n] = (f32x4){0.f, 0.f, 0.f, 0.f};

  const int ar = tid >> 1, ah = tid & 1;
  const int bn = tid & 127, bg = (tid >> 7) * 2;

  float4 ra[2][2];
  float rb[2][8];
  // prologue load (tile 0)
#pragma unroll
  for (int t2 = 0; t2 < 2; ++t2) {
    const float* ap = A + (size_t)(row0 + ar) * K + (ah * 2 + t2) * 8;
    ra[t2][0] = *(const float4*)ap;
    ra[t2][1] = *(const float4*)(ap + 4);
  }
#pragma unroll
  for (int t2 = 0; t2 < 2; ++t2) {
    const float* bp = B + (size_t)((bg + t2) * 8) * N + col0 + bn;
#pragma unroll
    for (int m2 = 0; m2 < 8; ++m2) rb[t2][m2] = bp[(size_t)m2 * N];
  }

  for (int k0 = 0; k0 < K; k0 += 32) {
    if (k0) __syncthreads();
    // write staged regs -> LDS (cvt f32->f16)
#pragma unroll
    for (int t2 = 0; t2 < 2; ++t2) {
      f16x8 pk;
      pk[0] = (_Float16)ra[t2][0].x; pk[1] = (_Float16)ra[t2][0].y;
      pk[2] = (_Float16)ra[t2][0].z; pk[3] = (_Float16)ra[t2][0].w;
      pk[4] = (_Float16)ra[t2][1].x; pk[5] = (_Float16)ra[t2][1].y;
      pk[6] = (_Float16)ra[t2][1].z; pk[7] = (_Float16)ra[t2][1].w;
      *(f16x8*)(As + swz(ar, (ah * 2 + t2) * 8)) = pk;
    }
#pragma unroll
    for (int t2 = 0; t2 < 2; ++t2) {
      f16x8 pk;
#pragma unroll
      for (int m2 = 0; m2 < 8; ++m2) pk[m2] = (_Float16)rb[t2][m2];
      *(f16x8*)(Bs + swz(bn, (bg + t2) * 8)) = pk;
    }
    __syncthreads();
    // issue next tile's loads (fly during MFMAs)
    if (k0 + 32 < K) {
#pragma unroll
      for (int t2 = 0; t2 < 2; ++t2) {
        const float* ap = A + (size_t)(row0 + ar) * K + k0 + 32 + (ah * 2 + t2) * 8;
        ra[t2][0] = *(const float4*)ap;
        ra[t2][1] = *(const float4*)(ap + 4);
      }
#pragma unroll
      for (int t2 = 0; t2 < 2; ++t2) {
        const float* bp = B + (size_t)(k0 + 32 + (bg + t2) * 8) * N + col0 + bn;
#pragma unroll
        for (int m2 = 0; m2 < 8; ++m2) rb[t2][m2] = bp[(size_t)m2 * N];
      }
    }
    f16x8 af[4], bfv[4];
#pragma unroll
    for (int m = 0; m < 4; ++m) af[m] = *(const f16x8*)(As + swz(wr * 64 + m * 16 + l16, g * 8));
#pragma unroll
    for (int n = 0; n < 4; ++n) bfv[n] = *(const f16x8*)(Bs + swz(wc * 64 + n * 16 + l16, g * 8));
#pragma unroll
    for (int m = 0; m < 4; ++m)
#pragma unroll
      for (int n = 0; n < 4; ++n)
        acc[m][n] = __builtin_amdgcn_mfma_f32_16x16x32_f16(af[m], bfv[n], acc[m][n], 0, 0, 0);
  }
#pragma unroll
  for (int m = 0; m < 4; ++m) {
#pragma unroll
    for (int n = 0; n < 4; ++n) {
      const int col = col0 + wc * 64 + n * 16 + l16;
      const float bv = bias ? bias[col] : 0.f;
#pragma unroll
      for (int rg = 0; rg < 4; ++rg) {
        const int row = row0 + wr * 64 + m * 16 + g * 4 + rg;
        const size_t off = (size_t)row * N + col;
        float v = acc[m][n][rg] + bv;
        if (residual) v += residual[off];
        if (act == 1) v = 0.5f * v * (1.f + erff(v * 0.70710678118654752f));
        if (store16) ((_Float16*)Cv)[off] = (_Float16)v;
        else ((float*)Cv)[off] = v;
      }
    }
  }
}

// ---------------- split-K GEMM: atomicAdd partials into fp32 acc buffer ----------------
// AF16: A operand is _Float16 (pre-converted). blockIdx.y = K-chunk.
template <int AF16>
__global__ __launch_bounds__(256) void gemm_sk(
    const void* __restrict__ Av, const float* __restrict__ B,
    float* __restrict__ Cacc, int M, int N, int K, int Kc, int gx) {
  __shared__ __align__(16) _Float16 As[128 * 32];
  __shared__ __align__(16) _Float16 Bs[128 * 32];
  const int tid = threadIdx.x;
  const int lane = tid & 63;
  const int wid = tid >> 6;
  const int wr = wid >> 1, wc = wid & 1;
  const int g = lane >> 4, l16 = lane & 15;
  const int cpx = gridDim.x >> 3;
  const int wg = (blockIdx.x & 7) * cpx + (blockIdx.x >> 3);
  const int row0 = (wg / gx) * 128, col0 = (wg % gx) * 128;
  const int kbeg = blockIdx.y * Kc, kend = kbeg + Kc;

  f32x4 acc[4][4];
#pragma unroll
  for (int m = 0; m < 4; ++m)
#pragma unroll
    for (int n = 0; n < 4; ++n) acc[m][n] = (f32x4){0.f, 0.f, 0.f, 0.f};

  const int ar = tid >> 1, ah = tid & 1;
  const int bn = tid & 127, bg = (tid >> 7) * 2;

  float4 ra[2][2];
  f16x8 ra16[2];
  float rb[2][8];
  if (AF16) {
    const _Float16* A16 = (const _Float16*)Av;
#pragma unroll
    for (int t2 = 0; t2 < 2; ++t2)
      ra16[t2] = *(const f16x8*)(A16 + (size_t)(row0 + ar) * K + kbeg + (ah * 2 + t2) * 8);
  } else {
    const float* A = (const float*)Av;
#pragma unroll
    for (int t2 = 0; t2 < 2; ++t2) {
      const float* ap = A + (size_t)(row0 + ar) * K + kbeg + (ah * 2 + t2) * 8;
      ra[t2][0] = *(const float4*)ap;
      ra[t2][1] = *(const float4*)(ap + 4);
    }
  }
#pragma unroll
  for (int t2 = 0; t2 < 2; ++t2) {
    const float* bp = B + (size_t)(kbeg + (bg + t2) * 8) * N + col0 + bn;
#pragma unroll
    for (int m2 = 0; m2 < 8; ++m2) rb[t2][m2] = bp[(size_t)m2 * N];
  }

  for (int k0 = kbeg; k0 < kend; k0 += 32) {
    if (k0 != kbeg) __syncthreads();
    if (AF16) {
#pragma unroll
      for (int t2 = 0; t2 < 2; ++t2)
        *(f16x8*)(As + swz(ar, (ah * 2 + t2) * 8)) = ra16[t2];
    } else {
#pragma unroll
      for (int t2 = 0; t2 < 2; ++t2) {
        f16x8 pk;
        pk[0] = (_Float16)ra[t2][0].x; pk[1] = (_Float16)ra[t2][0].y;
        pk[2] = (_Float16)ra[t2][0].z; pk[3] = (_Float16)ra[t2][0].w;
        pk[4] = (_Float16)ra[t2][1].x; pk[5] = (_Float16)ra[t2][1].y;
        pk[6] = (_Float16)ra[t2][1].z; pk[7] = (_Float16)ra[t2][1].w;
        *(f16x8*)(As + swz(ar, (ah * 2 + t2) * 8)) = pk;
      }
    }
#pragma unroll
    for (int t2 = 0; t2 < 2; ++t2) {
      f16x8 pk;
#pragma unroll
      for (int m2 = 0; m2 < 8; ++m2) pk[m2] = (_Float16)rb[t2][m2];
      *(f16x8*)(Bs + swz(bn, (bg + t2) * 8)) = pk;
    }
    __syncthreads();
    if (k0 + 32 < kend) {
      if (AF16) {
        const _Float16* A16 = (const _Float16*)Av;
#pragma unroll
        for (int t2 = 0; t2 < 2; ++t2)
          ra16[t2] = *(const f16x8*)(A16 + (size_t)(row0 + ar) * K + k0 + 32 + (ah * 2 + t2) * 8);
      } else {
        const float* A = (const float*)Av;
#pragma unroll
        for (int t2 = 0; t2 < 2; ++t2) {
          const float* ap = A + (size_t)(row0 + ar) * K + k0 + 32 + (ah * 2 + t2) * 8;
          ra[t2][0] = *(const float4*)ap;
          ra[t2][1] = *(const float4*)(ap + 4);
        }
      }
#pragma unroll
      for (int t2 = 0; t2 < 2; ++t2) {
        const float* bp = B + (size_t)(k0 + 32 + (bg + t2) * 8) * N + col0 + bn;
#pragma unroll
        for (int m2 = 0; m2 < 8; ++m2) rb[t2][m2] = bp[(size_t)m2 * N];
      }
    }
    f16x8 af[4], bfv[4];
#pragma unroll
    for (int m = 0; m < 4; ++m) af[m] = *(const f16x8*)(As + swz(wr * 64 + m * 16 + l16, g * 8));
#pragma unroll
    for (int n = 0; n < 4; ++n) bfv[n] = *(const f16x8*)(Bs + swz(wc * 64 + n * 16 + l16, g * 8));
#pragma unroll
    for (int m = 0; m < 4; ++m)
#pragma unroll
      for (int n = 0; n < 4; ++n)
        acc[m][n] = __builtin_amdgcn_mfma_f32_16x16x32_f16(af[m], bfv[n], acc[m][n], 0, 0, 0);
  }
#pragma unroll
  for (int m = 0; m < 4; ++m)
#pragma unroll
    for (int n = 0; n < 4; ++n) {
      const int col = col0 + wc * 64 + n * 16 + l16;
#pragma unroll
      for (int rg = 0; rg < 4; ++rg) {
        const int row = row0 + wr * 64 + m * 16 + g * 4 + rg;
        atomicAdd(&Cacc[(size_t)row * N + col], acc[m][n][rg]);
      }
    }
}

__global__ void zero_kernel(float4* __restrict__ p) {
  p[(size_t)blockIdx.x * 256 + threadIdx.x] = (float4){0.f, 0.f, 0.f, 0.f};
}

// out = acc + bias + res  (N = 1024)
__global__ void finalize_add(const float* __restrict__ acc, const float* __restrict__ bias,
                             const float* __restrict__ res, float* __restrict__ out) {
  const size_t i = (size_t)blockIdx.x * 256 + threadIdx.x;  // float4 index
  const int c4 = (int)(i & 255);
  const float4 a = ((const float4*)acc)[i];
  const float4 b = ((const float4*)bias)[c4];
  const float4 r = ((const float4*)res)[i];
  float4 o;
  o.x = a.x + b.x + r.x;
  o.y = a.y + b.y + r.y;
  o.z = a.z + b.z + r.z;
  o.w = a.w + b.w + r.w;
  ((float4*)out)[i] = o;
}

// ---------------- LayerNorm over D=1024, one row per 256-thread block ----------------
__global__ __launch_bounds__(256) void ln_kernel(const float* __restrict__ in,
    const float* __restrict__ gw, const float* __restrict__ bw, float* __restrict__ out) {
  const int row = blockIdx.x, tid = threadIdx.x;
  const float* x = in + (size_t)row * DD;
  const float4 v = *(const float4*)(x + tid * 4);
  float s = v.x + v.y + v.z + v.w;
  float sq = v.x * v.x + v.y * v.y + v.z * v.z + v.w * v.w;
#pragma unroll
  for (int off = 32; off >= 1; off >>= 1) { s += __shfl_xor(s, off); sq += __shfl_xor(sq, off); }
  __shared__ float red[8];
  const int lane = tid & 63, wv = tid >> 6;
  if (lane == 0) { red[wv] = s; red[4 + wv] = sq; }
  __syncthreads();
  s = red[0] + red[1] + red[2] + red[3];
  sq = red[4] + red[5] + red[6] + red[7];
  const float mean = s * (1.f / 1024.f);
  const float var = sq * (1.f / 1024.f) - mean * mean;
  const float rstd = rsqrtf(var + 1e-5f);
  const float4 g4 = *(const float4*)(gw + tid * 4);
  const float4 b4 = *(const float4*)(bw + tid * 4);
  float4 o;
  o.x = (v.x - mean) * rstd * g4.x + b4.x;
  o.y = (v.y - mean) * rstd * g4.y + b4.y;
  o.z = (v.z - mean) * rstd * g4.z + b4.z;
  o.w = (v.w - mean) * rstd * g4.w + b4.w;
  *(float4*)(out + (size_t)row * DD + tid * 4) = o;
}

// ---------------- MFMA f16 causal flash attention ----------------
static __device__ __forceinline__ int swzA(int row, int k) {
  return row * 64 + ((((k >> 3) ^ row) & 7) << 3) + (k & 7);
}
static __device__ __forceinline__ int swzV(int row, int k) {
  return row * 64 + ((((k >> 3) ^ row ^ (row >> 3)) & 7) << 3) + (k & 7);
}

__global__ __launch_bounds__(256) void attn_mfma(const float* __restrict__ qkv,
                                                 float* __restrict__ seq_out) {
  __shared__ __align__(16) _Float16 Kl[64 * 64];
  __shared__ __align__(16) _Float16 Vt[64 * 64];
  __shared__ __align__(16) _Float16 Pl[4][16 * 64];
  const int tid = threadIdx.x, lane = tid & 63, wq = tid >> 6;
  const int g = lane >> 4, l16 = lane & 15;
  const int qt = blockIdx.x, hh = blockIdx.y, bb = blockIdx.z;
  const int nt = qt + 1;

  f16x8 qf[2];
  {
    const float* qp = qkv + (size_t)(bb * TT + qt * 64 + wq * 16 + l16) * QS + hh * 64;
#pragma unroll
    for (int ks = 0; ks < 2; ++ks) {
      const float4 a0 = *(const float4*)(qp + ks * 32 + g * 8);
      const float4 a1 = *(const float4*)(qp + ks * 32 + g * 8 + 4);
      qf[ks][0] = (_Float16)(a0.x * 0.125f); qf[ks][1] = (_Float16)(a0.y * 0.125f);
      qf[ks][2] = (_Float16)(a0.z * 0.125f); qf[ks][3] = (_Float16)(a0.w * 0.125f);
      qf[ks][4] = (_Float16)(a1.x * 0.125f); qf[ks][5] = (_Float16)(a1.y * 0.125f);
      qf[ks][6] = (_Float16)(a1.z * 0.125f); qf[ks][7] = (_Float16)(a1.w * 0.125f);
    }
  }

  f32x4 oacc[4];
#pragma unroll
  for (int n = 0; n < 4; ++n) oacc[n] = (f32x4){0.f, 0.f, 0.f, 0.f};
  float m[4] = {-INFINITY, -INFINITY, -INFINITY, -INFINITY};
  float l[4] = {0.f, 0.f, 0.f, 0.f};

  const int skey = tid >> 2, sc4 = tid & 3;

  for (int tt = 0; tt < nt; ++tt) {
    if (tt) __syncthreads();
    {
      const float* kp = qkv + (size_t)(bb * TT + tt * 64 + skey) * QS + hh * 64 + 1024;
      const float* vp = kp + 1024;
#pragma unroll
      for (int ii = 0; ii < 4; ++ii) {
        const int d0 = sc4 * 4 + ii * 16;
        const float4 kv = *(const float4*)(kp + d0);
        f16x4 k4;
        k4[0] = (_Float16)kv.x; k4[1] = (_Float16)kv.y; k4[2] = (_Float16)kv.z; k4[3] = (_Float16)kv.w;
        *(f16x4*)(Kl + swzA(skey, d0)) = k4;
        const float4 vv = *(const float4*)(vp + d0);
        Vt[swzV(d0 + 0, skey)] = (_Float16)vv.x;
        Vt[swzV(d0 + 1, skey)] = (_Float16)vv.y;
        Vt[swzV(d0 + 2, skey)] = (_Float16)vv.z;
        Vt[swzV(d0 + 3, skey)] = (_Float16)vv.w;
      }
    }
    __syncthreads();
    f32x4 s[4];
#pragma unroll
    for (int n = 0; n < 4; ++n) s[n] = (f32x4){0.f, 0.f, 0.f, 0.f};
#pragma unroll
    for (int ks = 0; ks < 2; ++ks) {
      f16x8 kf[4];
#pragma unroll
      for (int n = 0; n < 4; ++n) kf[n] = *(const f16x8*)(Kl + swzA(n * 16 + l16, ks * 32 + g * 8));
#pragma unroll
      for (int n = 0; n < 4; ++n)
        s[n] = __builtin_amdgcn_mfma_f32_16x16x32_f16(qf[ks], kf[n], s[n], 0, 0, 0);
    }
    if (tt == qt) {
      const int rloc = wq * 16 + g * 4;
#pragma unroll
      for (int n = 0; n < 4; ++n) {
        const int cloc = n * 16 + l16;
#pragma unroll
        for (int reg = 0; reg < 4; ++reg)
          if (cloc > rloc + reg) s[n][reg] = -INFINITY;
      }
    }
    float f[4];
#pragma unroll
    for (int reg = 0; reg < 4; ++reg) {
      float t = fmaxf(fmaxf(s[0][reg], s[1][reg]), fmaxf(s[2][reg], s[3][reg]));
#pragma unroll
      for (int off = 1; off < 16; off <<= 1) t = fmaxf(t, __shfl_xor(t, off));
      const float nm = fmaxf(m[reg], t);
      f[reg] = __expf(m[reg] - nm);
      m[reg] = nm;
    }
    float rs[4] = {0.f, 0.f, 0.f, 0.f};
#pragma unroll
    for (int n = 0; n < 4; ++n) {
#pragma unroll
      for (int reg = 0; reg < 4; ++reg) {
        const float p = __expf(s[n][reg] - m[reg]);
        rs[reg] += p;
        Pl[wq][swzA(g * 4 + reg, n * 16 + l16)] = (_Float16)p;
      }
    }
#pragma unroll
    for (int reg = 0; reg < 4; ++reg) {
      float t = rs[reg];
#pragma unroll
      for (int off = 1; off < 16; off <<= 1) t += __shfl_xor(t, off);
      l[reg] = l[reg] * f[reg] + t;
    }
#pragma unroll
    for (int n = 0; n < 4; ++n)
#pragma unroll
      for (int reg = 0; reg < 4; ++reg) oacc[n][reg] *= f[reg];
#pragma unroll
    for (int ks = 0; ks < 2; ++ks) {
      const f16x8 pa = *(const f16x8*)(Pl[wq] + swzA(l16, ks * 32 + g * 8));
      f16x8 vb[4];
#pragma unroll
      for (int n = 0; n < 4; ++n) vb[n] = *(const f16x8*)(Vt + swzV(n * 16 + l16, ks * 32 + g * 8));
#pragma unroll
      for (int n = 0; n < 4; ++n)
        oacc[n] = __builtin_amdgcn_mfma_f32_16x16x32_f16(pa, vb[n], oacc[n], 0, 0, 0);
    }
  }
#pragma unroll
  for (int n = 0; n < 4; ++n) {
#pragma unroll
    for (int reg = 0; reg < 4; ++reg) {
      const int r = qt * 64 + wq * 16 + g * 4 + reg;
      seq_out[(size_t)(bb * TT + r) * DD + hh * 64 + n * 16 + l16] = oacc[n][reg] / l[reg];
    }
  }
}

// ---------------- build Wmega [1024][4608] ----------------
__global__ void prep_mega(const float* __restrict__ Wqkv, const float* __restrict__ bqkv,
                          const float* __restrict__ W1w, const float* __restrict__ W2w,
                          const float* __restrict__ W1r, const float* __restrict__ W2r,
                          const float* __restrict__ Wmg, const float* __restrict__ bmg,
                          const float* __restrict__ Wmv, const float* __restrict__ bmv,
                          float* __restrict__ Wm, float* __restrict__ bm) {
  const int col = blockIdx.x * 256 + threadIdx.x;  // 0..4607
  const int row = blockIdx.y;                      // 0..1024 (1024 = bias)
  if (row < 1024) {
    float v;
    if (col < 3072) v = Wqkv[(size_t)row * 3072 + col];
    else if (col < 3136) v = W1w[row * 64 + col - 3072];
    else if (col < 3200) v = W2w[row * 64 + col - 3136];
    else if (col < 3264) v = W1r[row * 64 + col - 3200];
    else if (col < 3328) v = W2r[row * 64 + col - 3264];
    else if (col < 3344) v = Wmg[row * 16 + col - 3328];
    else if (col < 3584) v = 0.f;
    else v = Wmv[(size_t)row * 1024 + col - 3584];
    Wm[(size_t)row * 4608 + col] = v;
  } else {
    float b = 0.f;
    if (col < 3072) b = bqkv[col];
    else if (col >= 3328 && col < 3344) b = bmg[col - 3328];
    else if (col >= 3584) b = bmv[col - 3584];
    bm[col] = b;
  }
}

// ---------------- exterior products -> Jw, rd, gate ----------------
static __device__ __forceinline__ void ext6(const float* a, const float* b, float* L) {
  L[0] = a[0] * b[1] - a[1] * b[0];
  L[1] = a[0] * b[2] - a[2] * b[0];
  L[2] = a[0] * b[3] - a[3] * b[0];
  L[3] = a[1] * b[2] - a[2] * b[1];
  L[4] = a[1] * b[3] - a[3] * b[1];
  L[5] = a[2] * b[3] - a[3] * b[2];
  const float n = sqrtf(L[0]*L[0] + L[1]*L[1] + L[2]*L[2] + L[3]*L[3] + L[4]*L[4] + L[5]*L[5]);
  const float s = 1.f / fmaxf(n, 1e-12f);
#pragma unroll
  for (int i = 0; i < 6; ++i) L[i] *= s;
}

__global__ void lines_post(const float* __restrict__ mega, float* __restrict__ jw,
                           float* __restrict__ rdv, float* __restrict__ gate) {
  const int idx = blockIdx.x * 256 + threadIdx.x;  // (b*T+t)*16 + h
  const int h = idx & 15;
  const int bt = idx >> 4;
  const int t = bt & 1023;
  const int b = bt >> 10;
  const float* row = mega + (size_t)bt * QS + 3072;
  float w1[4] = {0.f, 0.f, 0.f, 0.f}, w2[4], r1[4], r2[4];
  if (t > 0) {
#pragma unroll
    for (int i = 0; i < 4; ++i) w1[i] = row[-QS + h * 4 + i];
  }
#pragma unroll
  for (int i = 0; i < 4; ++i) {
    w2[i] = row[64 + h * 4 + i];
    r1[i] = row[128 + h * 4 + i];
    r2[i] = row[192 + h * 4 + i];
  }
  const float gp = row[256 + h];
  float wl[6], rl[6];
  ext6(w1, w2, wl);
  ext6(r1, r2, rl);
  const size_t o = ((size_t)(b * 16 + h) * 1024 + t) * 6;
  jw[o + 0] =  wl[5]; jw[o + 1] = -wl[4]; jw[o + 2] =  wl[3];
  jw[o + 3] =  wl[2]; jw[o + 4] = -wl[1]; jw[o + 5] =  wl[0];
#pragma unroll
  for (int i = 0; i < 6; ++i) rdv[o + i] = rl[i];
  gate[idx] = 1.f / (1.f + __expf(-gp));
}

// ---------------- chunk-parallel Gram scan ----------------
static __device__ __forceinline__ int midx(int i, int j) {
  return (i <= j) ? (i * (13 - i)) / 2 + (j - i) : (j * (13 - j)) / 2 + (i - j);
}

__global__ __launch_bounds__(64) void gram_scan(const float* __restrict__ jwv,
    const float* __restrict__ rdv, const float* __restrict__ decay_logits,
    const float* __restrict__ iter_mix, float* __restrict__ mem_score) {
  const int h = blockIdx.x & 15, b = blockIdx.x >> 4;
  const int lane = threadIdx.x;
  const float decay = 1.f / (1.f + __expf(-decay_logits[h]));
  const float alpha = 1.f / (1.f + __expf(-iter_mix[0]));
  __shared__ float sd[64 * 193];
  const size_t base = (size_t)(b * 16 + h) * 1024 * 6;
  for (int it = 0; it < 96; ++it) {
    const int idx = it * 64 + lane;
    const int t = idx / 6, i = idx - 6 * t;
    const int ld = t >> 4, s = t & 15;
    sd[ld * 193 + s * 6 + i] = jwv[base + idx];
    sd[ld * 193 + 96 + s * 6 + i] = rdv[base + idx];
  }
  __syncthreads();
  const float* seg = sd + lane * 193;

  float C[21];
#pragma unroll
  for (int e = 0; e < 21; ++e) C[e] = 0.f;
  for (int s = 0; s < 16; ++s) {
    float J[6], dJ[6];
#pragma unroll
    for (int i = 0; i < 6; ++i) { J[i] = seg[s * 6 + i]; dJ[i] = decay * J[i]; }
#pragma unroll
    for (int i = 0; i < 6; ++i)
#pragma unroll
      for (int j = i; j < 6; ++j)
        C[midx(i, j)] = decay * C[midx(i, j)] + dJ[i] * J[j];
  }
  const float d2 = decay * decay, d4 = d2 * d2, d8 = d4 * d4;
  float fk = d8 * d8;  // d^16
#pragma unroll
  for (int k = 0; k < 6; ++k) {
    const int off = 1 << k;
#pragma unroll
    for (int e = 0; e < 21; ++e) {
      const float u = __shfl(C[e], lane - off);
      if (lane >= off) C[e] += fk * u;
    }
    fk = fk * fk;
  }
  float M[21];
#pragma unroll
  for (int e = 0; e < 21; ++e) {
    const float u = __shfl(C[e], lane - 1);
    M[e] = (lane >= 1) ? u : 0.f;
  }
  float* msp = mem_score + (size_t)(b * 16 + h) * 1024 + lane * 16;
  for (int s = 0; s < 16; ++s) {
    float J[6], r[6];
#pragma unroll
    for (int i = 0; i < 6; ++i) { J[i] = seg[s * 6 + i]; r[i] = seg[96 + s * 6 + i]; }
    float rdM[6];
#pragma unroll
    for (int i = 0; i < 6; ++i) {
      float a = 0.f;
#pragma unroll
      for (int j = 0; j < 6; ++j) a += M[midx(i, j)] * r[j];
      rdM[i] = a;
    }
    float s1 = 0.f, s2 = 0.f;
#pragma unroll
    for (int i = 0; i < 6; ++i) { s1 += rdM[i] * r[i]; s2 += rdM[i] * rdM[i]; }
    msp[s] = (1.f - alpha) * s1 + alpha * s2;
    float dJ[6];
#pragma unroll
    for (int i = 0; i < 6; ++i) dJ[i] = decay * J[i];
#pragma unroll
    for (int i = 0; i < 6; ++i)
#pragma unroll
      for (int j = i; j < 6; ++j)
        M[midx(i, j)] = decay * M[midx(i, j)] + dJ[i] * J[j];
  }
}

// ---------------- gated mean over heads ----------------
__global__ void gmean_kernel(const float* __restrict__ ms, const float* __restrict__ gate,
    const float* __restrict__ mem_scale, float* __restrict__ gm) {
  const int bt = blockIdx.x * 256 + threadIdx.x;
  const int b = bt >> 10, t = bt & 1023;
  float acc = 0.f;
#pragma unroll
  for (int h = 0; h < 16; ++h) {
    const float sc = ms[(size_t)(b * 16 + h) * 1024 + t];
    const float gt = gate[(size_t)bt * 16 + h];
    acc += (1.f / (1.f + __expf(-sc * mem_scale[h]))) * gt;
  }
  gm[bt] = acc * (1.f / 16.f);
}

// ---------------- attnin = seq_out + gmean * mem_val ----------------
__global__ void combine_kernel(const float* __restrict__ seq, const float* __restrict__ mega,
    const float* __restrict__ gm, float* __restrict__ outp) {
  const int i = blockIdx.x * 256 + threadIdx.x;
  const int bt = i >> 8, c4 = i & 255;
  const float g = gm[bt];
  const float4 s4 = *(const float4*)(seq + (size_t)i * 4);
  const float4 m4 = *(const float4*)(mega + (size_t)bt * QS + 3584 + c4 * 4);
  float4 o;
  o.x = s4.x + g * m4.x;
  o.y = s4.y + g * m4.y;
  o.z = s4.z + g * m4.z;
  o.w = s4.w + g * m4.w;
  *(float4*)(outp + (size_t)i * 4) = o;
}

extern "C" void kernel_launch(void* const* d_in, const int* in_sizes, int n_in,
                              void* d_out, int out_size, void* d_ws, size_t ws_size,
                              hipStream_t stream) {
  (void)in_sizes; (void)n_in; (void)out_size; (void)ws_size;
  const float* x       = (const float*)d_in[0];
  const float* ln1_g   = (const float*)d_in[1];
  const float* ln1_b   = (const float*)d_in[2];
  const float* Wqkv    = (const float*)d_in[3];
  const float* bqkv    = (const float*)d_in[4];
  const float* W1w     = (const float*)d_in[5];
  const float* W2w     = (const float*)d_in[6];
  const float* W1r     = (const float*)d_in[7];
  const float* W2r     = (const float*)d_in[8];
  const float* Wmv     = (const float*)d_in[9];
  const float* bmv     = (const float*)d_in[10];
  const float* Wmg     = (const float*)d_in[11];
  const float* bmg     = (const float*)d_in[12];
  const float* mscale  = (const float*)d_in[13];
  const float* itermix = (const float*)d_in[14];
  const float* dlogits = (const float*)d_in[15];
  const float* Wout    = (const float*)d_in[16];
  const float* bout    = (const float*)d_in[17];
  const float* ln2_g   = (const float*)d_in[18];
  const float* ln2_b   = (const float*)d_in[19];
  const float* Wfc     = (const float*)d_in[20];
  const float* bfc     = (const float*)d_in[21];
  const float* Wproj   = (const float*)d_in[22];
  const float* bproj   = (const float*)d_in[23];
  float* out = (float*)d_out;
  float* ws = (float*)d_ws;

  const size_t M1 = 1u << 20;
  float* h     = ws;                        // 0..2M1   (h / h2)
  float* mega  = ws + 2 * M1;               // 2M1..11M1 (2048x4608)
  float* accW  = ws + 2 * M1;               // 2M1..4M1  (after mega dead)
  _Float16* fc16 = (_Float16*)(ws + 2 * M1);// 2M1..6M1  (2048x4096 f16; after accW dead)
  float* accP  = ws;                        // 0..2M1    (after h dead)
  float* Wm    = ws + 11 * M1;              // 11M1..15.5M1 [dead after mega GEMM]
  float* bm    = ws + 11 * M1 + 4718592;
  float* seq   = ws + 11 * M1;              // 2M1 floats (overlaps dead Wm)
  float* y     = ws + 13 * M1;              // 2M1 floats
  float* jw    = ws + 15 * M1;              // 196608
  float* rd    = ws + 15 * M1 + 196608;     // 196608
  float* gate  = ws + 15 * M1 + 393216;     // 32768
  float* ms    = ws + 15 * M1 + 425984;     // 32768
  float* gm    = ws + 15 * M1 + 458752;     // 2048

  prep_mega<<<dim3(18, 1025), 256, 0, stream>>>(Wqkv, bqkv, W1w, W2w, W1r, W2r,
                                                Wmg, bmg, Wmv, bmv, Wm, bm);
  ln_kernel<<<2048, 256, 0, stream>>>(x, ln1_g, ln1_b, h);
  gemm_f16<<<576, 256, 0, stream>>>(h, Wm, bm, nullptr, mega, 2048, 4608, 1024, 0, 36, 0);
  attn_mfma<<<dim3(16, 16, 2), 256, 0, stream>>>(mega, seq);
  lines_post<<<128, 256, 0, stream>>>(mega, jw, rd, gate);
  gram_scan<<<32, 64, 0, stream>>>(jw, rd, dlogits, itermix, ms);
  gmean_kernel<<<8, 256, 0, stream>>>(ms, gate, mscale, gm);
  combine_kernel<<<2048, 256, 0, stream>>>(seq, mega, gm, h);
  // y = attnin @ Wout + bout + x   (split-K=4, atomic acc)
  zero_kernel<<<2048, 256, 0, stream>>>((float4*)accW);
  gemm_sk<0><<<dim3(128, 4), 256, 0, stream>>>(h, Wout, accW, 2048, 1024, 1024, 256, 8);
  finalize_add<<<2048, 256, 0, stream>>>(accW, bout, x, y);
  ln_kernel<<<2048, 256, 0, stream>>>(y, ln2_g, ln2_b, h);
  // fc = gelu(h2 @ Wfc + bfc), stored f16
  gemm_f16<<<512, 256, 0, stream>>>(h, Wfc, bfc, nullptr, fc16, 2048, 4096, 1024, 1, 32, 1);
  // out = fc @ Wproj + bproj + y   (split-K=4, f16 A, atomic acc)
  zero_kernel<<<2048, 256, 0, stream>>>((float4*)accP);
  gemm_sk<1><<<dim3(128, 4), 256, 0, stream>>>(fc16, Wproj, accP, 2048, 1024, 4096, 1024, 8);
  finalize_add<<<2048, 256, 0, stream>>>(accP, bproj, y, out);
}

// Round 6
// 258.709 us; speedup vs baseline: 3.5654x; 1.1673x over previous
//
#include <hip/hip_runtime.h>
#include <hip/hip_bf16.h>
#include <math.h>

typedef float f32x4 __attribute__((ext_vector_type(4)));
typedef _Float16 f16x8 __attribute__((ext_vector_type(8)));
typedef _Float16 f16x4 __attribute__((ext_vector_type(4)));

#define TT 1024
#define DD 1024
#define QS 4608   // mega row stride (f16): [qkv 3072 | lines 512 | mv 1024]

typedef __attribute__((address_space(1))) const void gas_void;
typedef __attribute__((address_space(3))) void las_void;
static __device__ __forceinline__ void gl_lds16(const void* g, void* l) {
  __builtin_amdgcn_global_load_lds((gas_void*)g, (las_void*)l, 16, 0, 0);
}

// ============ f16 GEMM, m97 structure: 128x128 tile, BK=32, global_load_lds ============
// A[M][K] f16, Wt[N][K] f16 (pre-transposed weights). C = A·Wt^T (+bias)(+gelu).
// LDS linear [row][4 chunks of 8 f16]; content pre-swizzled: pos(row,q) holds chunk q^((row>>1)&3).
// mode: 1 = store f16, 2 = atomicAdd f32 (into pre-initialized buffer; bias ignored)
__global__ __launch_bounds__(256) void gemm_t16(
    const _Float16* __restrict__ A, const _Float16* __restrict__ Wt,
    const float* __restrict__ bias, void* __restrict__ Cv,
    int N, int K, int act, int gx, int mode, int ktiles) {
  __shared__ __align__(16) _Float16 As[128 * 32];
  __shared__ __align__(16) _Float16 Bs[128 * 32];
  const int tid = threadIdx.x;
  const int lane = tid & 63;
  const int wid = tid >> 6;
  const int wr = wid >> 1, wc = wid & 1;
  const int g = lane >> 4, l16 = lane & 15;
  const int cpx = gridDim.x >> 3;
  const int wg = (blockIdx.x & 7) * cpx + (blockIdx.x >> 3);   // XCD swizzle
  const int row0 = (wg / gx) * 128, col0 = (wg % gx) * 128;
  const int kbeg = blockIdx.y * ktiles * 32;

  f32x4 acc[4][4];
#pragma unroll
  for (int m = 0; m < 4; ++m)
#pragma unroll
    for (int n = 0; n < 4; ++n) acc[m][n] = (f32x4){0.f, 0.f, 0.f, 0.f};

  const int prm = (l16 >> 1) & 3;  // fragment-read chunk perm

  for (int kt = 0; kt < ktiles; ++kt) {
    if (kt) __syncthreads();
    const int kp = kbeg + kt * 32;
    // stage A and B tiles: 2 issues each, linear LDS dest, pre-swizzled global src
#pragma unroll
    for (int i = 0; i < 2; ++i) {
      const int rr = i * 64 + (tid >> 2);
      const int qq = (tid & 3) ^ ((rr >> 1) & 3);
      gl_lds16(A + (size_t)(row0 + rr) * K + kp + (qq << 3),
               (char*)As + (i * 256 + wid * 64) * 16);
      gl_lds16(Wt + (size_t)(col0 + rr) * K + kp + (qq << 3),
               (char*)Bs + (i * 256 + wid * 64) * 16);
    }
    __syncthreads();   // drains vmcnt before any wave reads
    f16x8 af[4], bf[4];
#pragma unroll
    for (int m = 0; m < 4; ++m) {
      const int r = wr * 64 + m * 16 + l16;
      af[m] = *(const f16x8*)(As + r * 32 + ((g ^ prm) << 3));
    }
#pragma unroll
    for (int n = 0; n < 4; ++n) {
      const int r = wc * 64 + n * 16 + l16;
      bf[n] = *(const f16x8*)(Bs + r * 32 + ((g ^ prm) << 3));
    }
#pragma unroll
    for (int m = 0; m < 4; ++m)
#pragma unroll
      for (int n = 0; n < 4; ++n)
        acc[m][n] = __builtin_amdgcn_mfma_f32_16x16x32_f16(af[m], bf[n], acc[m][n], 0, 0, 0);
  }
#pragma unroll
  for (int m = 0; m < 4; ++m) {
#pragma unroll
    for (int n = 0; n < 4; ++n) {
      const int col = col0 + wc * 64 + n * 16 + l16;
      const float bv = (mode != 2 && bias) ? bias[col] : 0.f;
#pragma unroll
      for (int rg = 0; rg < 4; ++rg) {
        const int row = row0 + wr * 64 + m * 16 + g * 4 + rg;
        const size_t off = (size_t)row * N + col;
        float v = acc[m][n][rg] + bv;
        if (act == 1) v = 0.5f * v * (1.f + erff(v * 0.70710678118654752f));
        if (mode == 2) atomicAdd(&((float*)Cv)[off], v);
        else ((_Float16*)Cv)[off] = (_Float16)v;
      }
    }
  }
}

// ============ weight transpose+convert: W[K][N] f32 -> WT[N][K] f16 ============
__global__ __launch_bounds__(256) void transT(const float* __restrict__ W,
                                              _Float16* __restrict__ WT, int K, int N) {
  __shared__ float tile[64][65];
  const int n0 = blockIdx.x * 64, k0 = blockIdx.y * 64;
  const int tn = threadIdx.x & 63, tk4 = threadIdx.x >> 6;
#pragma unroll
  for (int it = 0; it < 16; ++it) {
    const int k = k0 + it * 4 + tk4;
    tile[tn][it * 4 + tk4] = W[(size_t)k * N + n0 + tn];
  }
  __syncthreads();
  const int on = threadIdx.x >> 2, ok = threadIdx.x & 3;
  f16x8 a, b;
#pragma unroll
  for (int j = 0; j < 8; ++j) {
    a[j] = (_Float16)tile[on][ok * 16 + j];
    b[j] = (_Float16)tile[on][ok * 16 + 8 + j];
  }
  _Float16* dst = WT + (size_t)(n0 + on) * K + k0 + ok * 16;
  *(f16x8*)dst = a;
  *(f16x8*)(dst + 8) = b;
}

// ============ build WmT [4608][1024] f16 (transposed mega weight) ============
__global__ __launch_bounds__(256) void prep_megaT(
    const float* __restrict__ Wqkv, const float* __restrict__ W1w, const float* __restrict__ W2w,
    const float* __restrict__ W1r, const float* __restrict__ W2r, const float* __restrict__ Wmg,
    const float* __restrict__ Wmv, _Float16* __restrict__ WmT) {
  __shared__ float tile[64][65];
  const int n0 = blockIdx.x * 64, k0 = blockIdx.y * 64;
  const int tn = threadIdx.x & 63, tk4 = threadIdx.x >> 6;
#pragma unroll
  for (int it = 0; it < 16; ++it) {
    const int k = k0 + it * 4 + tk4;
    const int n = n0 + tn;
    float v;
    if (n < 3072) v = Wqkv[(size_t)k * 3072 + n];
    else if (n < 3136) v = W1w[k * 64 + n - 3072];
    else if (n < 3200) v = W2w[k * 64 + n - 3136];
    else if (n < 3264) v = W1r[k * 64 + n - 3200];
    else if (n < 3328) v = W2r[k * 64 + n - 3264];
    else if (n < 3344) v = Wmg[k * 16 + n - 3328];
    else if (n < 3584) v = 0.f;
    else v = Wmv[(size_t)k * 1024 + n - 3584];
    tile[tn][it * 4 + tk4] = v;
  }
  __syncthreads();
  const int on = threadIdx.x >> 2, ok = threadIdx.x & 3;
  f16x8 a, b;
#pragma unroll
  for (int j = 0; j < 8; ++j) {
    a[j] = (_Float16)tile[on][ok * 16 + j];
    b[j] = (_Float16)tile[on][ok * 16 + 8 + j];
  }
  _Float16* dst = WmT + (size_t)(n0 + on) * 1024 + k0 + ok * 16;
  *(f16x8*)dst = a;
  *(f16x8*)(dst + 8) = b;
}

__global__ void bm_init(const float* __restrict__ bqkv, const float* __restrict__ bmg,
                        const float* __restrict__ bmv, float* __restrict__ bm) {
  const int col = blockIdx.x * 256 + threadIdx.x;
  if (col >= 4608) return;
  float b = 0.f;
  if (col < 3072) b = bqkv[col];
  else if (col >= 3328 && col < 3344) b = bmg[col - 3328];
  else if (col >= 3584) b = bmv[col - 3584];
  bm[col] = b;
}

// ============ LayerNorm -> f16 ============
__global__ __launch_bounds__(256) void ln16(const float* __restrict__ in,
    const float* __restrict__ gw, const float* __restrict__ bw, _Float16* __restrict__ out) {
  const int row = blockIdx.x, tid = threadIdx.x;
  const float* x = in + (size_t)row * DD;
  const float4 v = *(const float4*)(x + tid * 4);
  float s = v.x + v.y + v.z + v.w;
  float sq = v.x * v.x + v.y * v.y + v.z * v.z + v.w * v.w;
#pragma unroll
  for (int off = 32; off >= 1; off >>= 1) { s += __shfl_xor(s, off); sq += __shfl_xor(sq, off); }
  __shared__ float red[8];
  const int lane = tid & 63, wv = tid >> 6;
  if (lane == 0) { red[wv] = s; red[4 + wv] = sq; }
  __syncthreads();
  s = red[0] + red[1] + red[2] + red[3];
  sq = red[4] + red[5] + red[6] + red[7];
  const float mean = s * (1.f / 1024.f);
  const float var = sq * (1.f / 1024.f) - mean * mean;
  const float rstd = rsqrtf(var + 1e-5f);
  const float4 g4 = *(const float4*)(gw + tid * 4);
  const float4 b4 = *(const float4*)(bw + tid * 4);
  f16x4 o;
  o[0] = (_Float16)((v.x - mean) * rstd * g4.x + b4.x);
  o[1] = (_Float16)((v.y - mean) * rstd * g4.y + b4.y);
  o[2] = (_Float16)((v.z - mean) * rstd * g4.z + b4.z);
  o[3] = (_Float16)((v.w - mean) * rstd * g4.w + b4.w);
  *(f16x4*)(out + (size_t)row * DD + tid * 4) = o;
}

// ============ MFMA f16 causal flash attention (f16 qkv input) ============
static __device__ __forceinline__ int swzA(int row, int k) {
  return row * 64 + ((((k >> 3) ^ row) & 7) << 3) + (k & 7);
}
static __device__ __forceinline__ int swzV(int row, int k) {
  return row * 64 + ((((k >> 3) ^ row ^ (row >> 3)) & 7) << 3) + (k & 7);
}

__global__ __launch_bounds__(256) void attn_mfma(const _Float16* __restrict__ qkv,
                                                 _Float16* __restrict__ seq_out) {
  __shared__ __align__(16) _Float16 Kl[64 * 64];
  __shared__ __align__(16) _Float16 Vt[64 * 64];
  __shared__ __align__(16) _Float16 Pl[4][16 * 64];
  const int tid = threadIdx.x, lane = tid & 63, wq = tid >> 6;
  const int g = lane >> 4, l16 = lane & 15;
  const int qt = blockIdx.x, hh = blockIdx.y, bb = blockIdx.z;
  const int nt = qt + 1;

  f16x8 qf[2];
  {
    const _Float16* qp = qkv + (size_t)(bb * TT + qt * 64 + wq * 16 + l16) * QS + hh * 64;
#pragma unroll
    for (int ks = 0; ks < 2; ++ks) {
      const f16x8 a = *(const f16x8*)(qp + ks * 32 + g * 8);
#pragma unroll
      for (int j = 0; j < 8; ++j) qf[ks][j] = (_Float16)((float)a[j] * 0.125f);
    }
  }

  f32x4 oacc[4];
#pragma unroll
  for (int n = 0; n < 4; ++n) oacc[n] = (f32x4){0.f, 0.f, 0.f, 0.f};
  float m[4] = {-INFINITY, -INFINITY, -INFINITY, -INFINITY};
  float l[4] = {0.f, 0.f, 0.f, 0.f};

  const int skey = tid >> 2, sc4 = tid & 3;

  for (int tt = 0; tt < nt; ++tt) {
    if (tt) __syncthreads();
    {
      const _Float16* kp = qkv + (size_t)(bb * TT + tt * 64 + skey) * QS + hh * 64 + 1024;
      const _Float16* vp = kp + 1024;
#pragma unroll
      for (int ii = 0; ii < 4; ++ii) {
        const int d0 = sc4 * 4 + ii * 16;
        *(f16x4*)(Kl + swzA(skey, d0)) = *(const f16x4*)(kp + d0);
        const f16x4 vv = *(const f16x4*)(vp + d0);
        Vt[swzV(d0 + 0, skey)] = vv[0];
        Vt[swzV(d0 + 1, skey)] = vv[1];
        Vt[swzV(d0 + 2, skey)] = vv[2];
        Vt[swzV(d0 + 3, skey)] = vv[3];
      }
    }
    __syncthreads();
    f32x4 s[4];
#pragma unroll
    for (int n = 0; n < 4; ++n) s[n] = (f32x4){0.f, 0.f, 0.f, 0.f};
#pragma unroll
    for (int ks = 0; ks < 2; ++ks) {
      f16x8 kf[4];
#pragma unroll
      for (int n = 0; n < 4; ++n) kf[n] = *(const f16x8*)(Kl + swzA(n * 16 + l16, ks * 32 + g * 8));
#pragma unroll
      for (int n = 0; n < 4; ++n)
        s[n] = __builtin_amdgcn_mfma_f32_16x16x32_f16(qf[ks], kf[n], s[n], 0, 0, 0);
    }
    if (tt == qt) {
      const int rloc = wq * 16 + g * 4;
#pragma unroll
      for (int n = 0; n < 4; ++n) {
        const int cloc = n * 16 + l16;
#pragma unroll
        for (int reg = 0; reg < 4; ++reg)
          if (cloc > rloc + reg) s[n][reg] = -INFINITY;
      }
    }
    float f[4];
#pragma unroll
    for (int reg = 0; reg < 4; ++reg) {
      float t = fmaxf(fmaxf(s[0][reg], s[1][reg]), fmaxf(s[2][reg], s[3][reg]));
#pragma unroll
      for (int off = 1; off < 16; off <<= 1) t = fmaxf(t, __shfl_xor(t, off));
      const float nm = fmaxf(m[reg], t);
      f[reg] = __expf(m[reg] - nm);
      m[reg] = nm;
    }
    float rs[4] = {0.f, 0.f, 0.f, 0.f};
#pragma unroll
    for (int n = 0; n < 4; ++n) {
#pragma unroll
      for (int reg = 0; reg < 4; ++reg) {
        const float p = __expf(s[n][reg] - m[reg]);
        rs[reg] += p;
        Pl[wq][swzA(g * 4 + reg, n * 16 + l16)] = (_Float16)p;
      }
    }
#pragma unroll
    for (int reg = 0; reg < 4; ++reg) {
      float t = rs[reg];
#pragma unroll
      for (int off = 1; off < 16; off <<= 1) t += __shfl_xor(t, off);
      l[reg] = l[reg] * f[reg] + t;
    }
#pragma unroll
    for (int n = 0; n < 4; ++n)
#pragma unroll
      for (int reg = 0; reg < 4; ++reg) oacc[n][reg] *= f[reg];
#pragma unroll
    for (int ks = 0; ks < 2; ++ks) {
      const f16x8 pa = *(const f16x8*)(Pl[wq] + swzA(l16, ks * 32 + g * 8));
      f16x8 vb[4];
#pragma unroll
      for (int n = 0; n < 4; ++n) vb[n] = *(const f16x8*)(Vt + swzV(n * 16 + l16, ks * 32 + g * 8));
#pragma unroll
      for (int n = 0; n < 4; ++n)
        oacc[n] = __builtin_amdgcn_mfma_f32_16x16x32_f16(pa, vb[n], oacc[n], 0, 0, 0);
    }
  }
#pragma unroll
  for (int n = 0; n < 4; ++n) {
#pragma unroll
    for (int reg = 0; reg < 4; ++reg) {
      const int r = qt * 64 + wq * 16 + g * 4 + reg;
      seq_out[(size_t)(bb * TT + r) * DD + hh * 64 + n * 16 + l16] = (_Float16)(oacc[n][reg] / l[reg]);
    }
  }
}

// ============ exterior products -> Jw, rd, gate (f16 mega input) ============
static __device__ __forceinline__ void ext6(const float* a, const float* b, float* L) {
  L[0] = a[0] * b[1] - a[1] * b[0];
  L[1] = a[0] * b[2] - a[2] * b[0];
  L[2] = a[0] * b[3] - a[3] * b[0];
  L[3] = a[1] * b[2] - a[2] * b[1];
  L[4] = a[1] * b[3] - a[3] * b[1];
  L[5] = a[2] * b[3] - a[3] * b[2];
  const float n = sqrtf(L[0]*L[0] + L[1]*L[1] + L[2]*L[2] + L[3]*L[3] + L[4]*L[4] + L[5]*L[5]);
  const float s = 1.f / fmaxf(n, 1e-12f);
#pragma unroll
  for (int i = 0; i < 6; ++i) L[i] *= s;
}

__global__ void lines_post(const _Float16* __restrict__ mega, float* __restrict__ jw,
                           float* __restrict__ rdv, float* __restrict__ gate) {
  const int idx = blockIdx.x * 256 + threadIdx.x;
  const int h = idx & 15;
  const int bt = idx >> 4;
  const int t = bt & 1023;
  const int b = bt >> 10;
  const _Float16* row = mega + (size_t)bt * QS + 3072;
  float w1[4] = {0.f, 0.f, 0.f, 0.f}, w2[4], r1[4], r2[4];
  if (t > 0) {
#pragma unroll
    for (int i = 0; i < 4; ++i) w1[i] = (float)row[-QS + h * 4 + i];
  }
#pragma unroll
  for (int i = 0; i < 4; ++i) {
    w2[i] = (float)row[64 + h * 4 + i];
    r1[i] = (float)row[128 + h * 4 + i];
    r2[i] = (float)row[192 + h * 4 + i];
  }
  const float gp = (float)row[256 + h];
  float wl[6], rl[6];
  ext6(w1, w2, wl);
  ext6(r1, r2, rl);
  const size_t o = ((size_t)(b * 16 + h) * 1024 + t) * 6;
  jw[o + 0] =  wl[5]; jw[o + 1] = -wl[4]; jw[o + 2] =  wl[3];
  jw[o + 3] =  wl[2]; jw[o + 4] = -wl[1]; jw[o + 5] =  wl[0];
#pragma unroll
  for (int i = 0; i < 6; ++i) rdv[o + i] = rl[i];
  gate[idx] = 1.f / (1.f + __expf(-gp));
}

// ============ chunk-parallel Gram scan ============
static __device__ __forceinline__ int midx(int i, int j) {
  return (i <= j) ? (i * (13 - i)) / 2 + (j - i) : (j * (13 - j)) / 2 + (i - j);
}

__global__ __launch_bounds__(64) void gram_scan(const float* __restrict__ jwv,
    const float* __restrict__ rdv, const float* __restrict__ decay_logits,
    const float* __restrict__ iter_mix, float* __restrict__ mem_score) {
  const int h = blockIdx.x & 15, b = blockIdx.x >> 4;
  const int lane = threadIdx.x;
  const float decay = 1.f / (1.f + __expf(-decay_logits[h]));
  const float alpha = 1.f / (1.f + __expf(-iter_mix[0]));
  __shared__ float sd[64 * 193];
  const size_t base = (size_t)(b * 16 + h) * 1024 * 6;
  for (int it = 0; it < 96; ++it) {
    const int idx = it * 64 + lane;
    const int t = idx / 6, i = idx - 6 * t;
    const int ld = t >> 4, s = t & 15;
    sd[ld * 193 + s * 6 + i] = jwv[base + idx];
    sd[ld * 193 + 96 + s * 6 + i] = rdv[base + idx];
  }
  __syncthreads();
  const float* seg = sd + lane * 193;

  float C[21];
#pragma unroll
  for (int e = 0; e < 21; ++e) C[e] = 0.f;
  for (int s = 0; s < 16; ++s) {
    float J[6], dJ[6];
#pragma unroll
    for (int i = 0; i < 6; ++i) { J[i] = seg[s * 6 + i]; dJ[i] = decay * J[i]; }
#pragma unroll
    for (int i = 0; i < 6; ++i)
#pragma unroll
      for (int j = i; j < 6; ++j)
        C[midx(i, j)] = decay * C[midx(i, j)] + dJ[i] * J[j];
  }
  const float d2 = decay * decay, d4 = d2 * d2, d8 = d4 * d4;
  float fk = d8 * d8;  // d^16
#pragma unroll
  for (int k = 0; k < 6; ++k) {
    const int off = 1 << k;
#pragma unroll
    for (int e = 0; e < 21; ++e) {
      const float u = __shfl(C[e], lane - off);
      if (lane >= off) C[e] += fk * u;
    }
    fk = fk * fk;
  }
  float M[21];
#pragma unroll
  for (int e = 0; e < 21; ++e) {
    const float u = __shfl(C[e], lane - 1);
    M[e] = (lane >= 1) ? u : 0.f;
  }
  float* msp = mem_score + (size_t)(b * 16 + h) * 1024 + lane * 16;
  for (int s = 0; s < 16; ++s) {
    float J[6], r[6];
#pragma unroll
    for (int i = 0; i < 6; ++i) { J[i] = seg[s * 6 + i]; r[i] = seg[96 + s * 6 + i]; }
    float rdM[6];
#pragma unroll
    for (int i = 0; i < 6; ++i) {
      float a = 0.f;
#pragma unroll
      for (int j = 0; j < 6; ++j) a += M[midx(i, j)] * r[j];
      rdM[i] = a;
    }
    float s1 = 0.f, s2 = 0.f;
#pragma unroll
    for (int i = 0; i < 6; ++i) { s1 += rdM[i] * r[i]; s2 += rdM[i] * rdM[i]; }
    msp[s] = (1.f - alpha) * s1 + alpha * s2;
    float dJ[6];
#pragma unroll
    for (int i = 0; i < 6; ++i) dJ[i] = decay * J[i];
#pragma unroll
    for (int i = 0; i < 6; ++i)
#pragma unroll
      for (int j = i; j < 6; ++j)
        M[midx(i, j)] = decay * M[midx(i, j)] + dJ[i] * J[j];
  }
}

// ============ gated mean over heads ============
__global__ void gmean_kernel(const float* __restrict__ ms, const float* __restrict__ gate,
    const float* __restrict__ mem_scale, float* __restrict__ gm) {
  const int bt = blockIdx.x * 256 + threadIdx.x;
  const int b = bt >> 10, t = bt & 1023;
  float acc = 0.f;
#pragma unroll
  for (int h = 0; h < 16; ++h) {
    const float sc = ms[(size_t)(b * 16 + h) * 1024 + t];
    const float gt = gate[(size_t)bt * 16 + h];
    acc += (1.f / (1.f + __expf(-sc * mem_scale[h]))) * gt;
  }
  gm[bt] = acc * (1.f / 16.f);
}

// ============ attnin = seq + gm*mv  (f16 out) ============
__global__ void combine_kernel(const _Float16* __restrict__ seq, const _Float16* __restrict__ mega,
    const float* __restrict__ gm, _Float16* __restrict__ outp) {
  const int i = blockIdx.x * 256 + threadIdx.x;  // f16x4 index, 524288 total
  const int bt = i >> 8, c4 = i & 255;
  const float g = gm[bt];
  const f16x4 s4 = *(const f16x4*)(seq + (size_t)i * 4);
  const f16x4 m4 = *(const f16x4*)(mega + (size_t)bt * QS + 3584 + c4 * 4);
  f16x4 o;
#pragma unroll
  for (int j = 0; j < 4; ++j) o[j] = (_Float16)((float)s4[j] + g * (float)m4[j]);
  *(f16x4*)(outp + (size_t)i * 4) = o;
}

// ============ dst = src + bias  (pre-init for atomic split-K GEMMs) ============
__global__ void addb_init(const float* __restrict__ src, const float* __restrict__ bias,
                          float* __restrict__ dst) {
  const size_t i = (size_t)blockIdx.x * 256 + threadIdx.x;  // float4 index
  const int c4 = (int)(i & 255);
  const float4 s = ((const float4*)src)[i];
  const float4 b = ((const float4*)bias)[c4];
  float4 o;
  o.x = s.x + b.x; o.y = s.y + b.y; o.z = s.z + b.z; o.w = s.w + b.w;
  ((float4*)dst)[i] = o;
}

extern "C" void kernel_launch(void* const* d_in, const int* in_sizes, int n_in,
                              void* d_out, int out_size, void* d_ws, size_t ws_size,
                              hipStream_t stream) {
  (void)in_sizes; (void)n_in; (void)out_size; (void)ws_size;
  const float* x       = (const float*)d_in[0];
  const float* ln1_g   = (const float*)d_in[1];
  const float* ln1_b   = (const float*)d_in[2];
  const float* Wqkv    = (const float*)d_in[3];
  const float* bqkv    = (const float*)d_in[4];
  const float* W1w     = (const float*)d_in[5];
  const float* W2w     = (const float*)d_in[6];
  const float* W1r     = (const float*)d_in[7];
  const float* W2r     = (const float*)d_in[8];
  const float* Wmv     = (const float*)d_in[9];
  const float* bmv     = (const float*)d_in[10];
  const float* Wmg     = (const float*)d_in[11];
  const float* bmg     = (const float*)d_in[12];
  const float* mscale  = (const float*)d_in[13];
  const float* itermix = (const float*)d_in[14];
  const float* dlogits = (const float*)d_in[15];
  const float* Wout    = (const float*)d_in[16];
  const float* bout    = (const float*)d_in[17];
  const float* ln2_g   = (const float*)d_in[18];
  const float* ln2_b   = (const float*)d_in[19];
  const float* Wfc     = (const float*)d_in[20];
  const float* bfc     = (const float*)d_in[21];
  const float* Wproj   = (const float*)d_in[22];
  const float* bproj   = (const float*)d_in[23];
  float* out = (float*)d_out;
  float* ws = (float*)d_ws;

  const size_t M1 = 1u << 20;
  _Float16* h16    = (_Float16*)ws;                         // 0 .. 1M1 (2M f16)
  _Float16* WmT    = (_Float16*)(ws + 1 * M1);              // 1M1 .. 3.25M1
  float*    bm     = ws + 3407872;                          // 3.25M1, 4608
  float*    jw     = ws + 3538944;                          // 3.375M1, 196608
  float*    rd     = ws + 3538944 + 196608;
  float*    gate   = ws + 3538944 + 393216;                 // 32768
  float*    ms     = ws + 3538944 + 425984;                 // 32768
  float*    gm     = ws + 3538944 + 458752;                 // 2048
  float*    y      = ws + 4 * M1;                           // 4M1 .. 6M1
  _Float16* mega   = (_Float16*)(ws + 6 * M1);              // 6M1 .. 10.5M1 (2048x4608 f16)
  _Float16* fc16   = (_Float16*)(ws + 6 * M1);              // reuses mega (dead by then)
  _Float16* seq16  = (_Float16*)(ws + 11010048);            // 10.5M1 .. 11.5M1
  _Float16* WoutT  = (_Float16*)(ws + 12058624);            // 11.5M1 .. 12M1
  _Float16* WfcT   = (_Float16*)(ws + 12 * M1);             // 12M1 .. 14M1 (4096x1024 f16)
  _Float16* WprojT = (_Float16*)(ws + 14 * M1);             // 14M1 .. 16M1 (1024x4096 f16)

  // ---- weight prep (transpose + f16) ----
  prep_megaT<<<dim3(72, 16), 256, 0, stream>>>(Wqkv, W1w, W2w, W1r, W2r, Wmg, Wmv, WmT);
  bm_init<<<18, 256, 0, stream>>>(bqkv, bmg, bmv, bm);
  transT<<<dim3(16, 16), 256, 0, stream>>>(Wout, WoutT, 1024, 1024);
  transT<<<dim3(64, 16), 256, 0, stream>>>(Wfc, WfcT, 1024, 4096);
  transT<<<dim3(16, 64), 256, 0, stream>>>(Wproj, WprojT, 4096, 1024);

  // ---- block ----
  ln16<<<2048, 256, 0, stream>>>(x, ln1_g, ln1_b, h16);
  gemm_t16<<<576, 256, 0, stream>>>(h16, WmT, bm, mega, 4608, 1024, 0, 36, 1, 32);
  attn_mfma<<<dim3(16, 16, 2), 256, 0, stream>>>(mega, seq16);
  lines_post<<<128, 256, 0, stream>>>(mega, jw, rd, gate);
  gram_scan<<<32, 64, 0, stream>>>(jw, rd, dlogits, itermix, ms);
  gmean_kernel<<<8, 256, 0, stream>>>(ms, gate, mscale, gm);
  combine_kernel<<<2048, 256, 0, stream>>>(seq16, mega, gm, h16);
  // y = x + bout + attnin @ Wout   (split-K=4 atomics into pre-initialized y)
  addb_init<<<2048, 256, 0, stream>>>(x, bout, y);
  gemm_t16<<<dim3(128, 4), 256, 0, stream>>>(h16, WoutT, nullptr, y, 1024, 1024, 0, 8, 2, 8);
  ln16<<<2048, 256, 0, stream>>>(y, ln2_g, ln2_b, h16);
  // fc = gelu(h2 @ Wfc + bfc), stored f16 (overwrites mega)
  gemm_t16<<<512, 256, 0, stream>>>(h16, WfcT, bfc, fc16, 4096, 1024, 1, 32, 1, 32);
  // out = y + bproj + fc @ Wproj   (split-K=4 atomics into pre-initialized out)
  addb_init<<<2048, 256, 0, stream>>>(y, bproj, out);
  gemm_t16<<<dim3(128, 4), 256, 0, stream>>>(fc16, WprojT, nullptr, out, 1024, 4096, 0, 8, 2, 32);
}